// Round 1
// baseline (866.817 us; speedup 1.0000x reference)
//
#include <hip/hip_runtime.h>

// ---------------- problem constants ----------------
// b=4, C=512, h=w=128, BH=BW=4 -> 64 instances, P=1024 pixels each
// CM=76 (pad 80), mid=256
#define CM_    76
#define CMP_   80

// ---------------- workspace layout (float offsets) ----------------
#define OFF_ROWMAX 0            // [64][76]
#define OFF_SCALE  4864         // [64][76]   conf/sumexp
#define OFF_LOCAL  9728         // [64][76][512]
#define OFF_KALL   2500096      // [65][76][256]  (inst 64 = v)
#define OFF_WQK    3764736      // [64][512][80]
#define OFF_BK2    6386176      // [64][80]
#define OFF_VW     6391296      // [80][512]
#define OFF_INV    6432256      // [512]
#define OFF_ADD    6432768      // [512]
// total = 6,433,280 floats = 25.7 MB of d_ws

// ---------------- K1: pooling + softmax stats ----------------
// grid (76, 64), block 256. Each block: one (cm, inst) row of 1024 pixels.
__global__ __launch_bounds__(256) void k1_stats(
    const float* __restrict__ sim, float* __restrict__ pcs,
    float* __restrict__ rowmax, float* __restrict__ scale_arr) {
  const int cm = blockIdx.x, inst = blockIdx.y;
  const int b = inst >> 4, n = inst & 15, bh = n >> 2, bw = n & 3;
  const float* base = sim + ((size_t)(b * CM_ + cm) << 14);
  const int t = threadIdx.x;
  float v[4];
  float lsum = 0.f, lmax = -1e30f;
#pragma unroll
  for (int i = 0; i < 4; ++i) {
    int p = t + (i << 8);
    int pix = ((bh * 32 + (p >> 5)) << 7) + bw * 32 + (p & 31);
    float xv = base[pix];
    v[i] = xv; lsum += xv; lmax = fmaxf(lmax, xv);
  }
#pragma unroll
  for (int off = 32; off; off >>= 1) {
    lsum += __shfl_down(lsum, off);
    lmax = fmaxf(lmax, __shfl_down(lmax, off));
  }
  __shared__ float ssum[4], smax[4], bc[2];
  const int wid = t >> 6;
  if ((t & 63) == 0) { ssum[wid] = lsum; smax[wid] = lmax; }
  __syncthreads();
  if (t == 0) {
    bc[0] = ssum[0] + ssum[1] + ssum[2] + ssum[3];
    bc[1] = fmaxf(fmaxf(smax[0], smax[1]), fmaxf(smax[2], smax[3]));
  }
  __syncthreads();
  const float M = bc[1];
  float le = 0.f;
#pragma unroll
  for (int i = 0; i < 4; ++i) le += __expf(v[i] - M);
#pragma unroll
  for (int off = 32; off; off >>= 1) le += __shfl_down(le, off);
  if ((t & 63) == 0) ssum[wid] = le;
  __syncthreads();
  if (t == 0) {
    float E = ssum[0] + ssum[1] + ssum[2] + ssum[3];
    float conf = bc[0] * (1.f / 1024.f);
    pcs[((b * CM_ + cm) << 4) + n] = conf;       // patch_cls_score output
    rowmax[inst * CM_ + cm] = M;
    scale_arr[inst * CM_ + cm] = conf / E;
  }
}

// ---------------- K2: local = conf * softmax(sm)^T @ xs ----------------
// grid (4, 64): x = 128-col tile, y = inst. block 256 (16x16), out tile 80x128.
__global__ __launch_bounds__(256) void k2_local(
    const float* __restrict__ x, const float* __restrict__ sim,
    const float* __restrict__ rowmax, const float* __restrict__ scale_arr,
    float* __restrict__ local_out) {
  const int cc = blockIdx.x, inst = blockIdx.y;
  const int b = inst >> 4, n = inst & 15, bh = n >> 2, bw = n & 3;
  __shared__ float A_s[CMP_ * 33];   // [80][33]
  __shared__ float B_s[32 * 129];    // [32][129]
  const int t = threadIdx.x, tx = t & 15, ty = t >> 4;
  float acc[5][8] = {};
  for (int k0 = 0; k0 < 1024; k0 += 32) {
    __syncthreads();
#pragma unroll
    for (int i = 0; i < 10; ++i) {      // A: 80x32 exp weights
      int idx = t + (i << 8);
      int cm = idx >> 5, k = idx & 31;
      float val = 0.f;
      if (cm < CM_) {
        int p = k0 + k;
        int pix = ((bh * 32 + (p >> 5)) << 7) + bw * 32 + (p & 31);
        val = __expf(sim[((size_t)(b * CM_ + cm) << 14) + pix] - rowmax[inst * CM_ + cm]);
      }
      A_s[cm * 33 + k] = val;
    }
#pragma unroll
    for (int i = 0; i < 16; ++i) {      // B: 32x128 of xs
      int idx = t + (i << 8);
      int k = idx & 31, c = idx >> 5;
      int p = k0 + k;
      int pix = ((bh * 32 + (p >> 5)) << 7) + bw * 32 + (p & 31);
      B_s[k * 129 + c] = x[((size_t)(b * 512 + cc * 128 + c) << 14) + pix];
    }
    __syncthreads();
#pragma unroll 8
    for (int k = 0; k < 32; ++k) {
      float a[5], bb[8];
#pragma unroll
      for (int pp = 0; pp < 5; ++pp) a[pp] = A_s[(ty + 16 * pp) * 33 + k];
#pragma unroll
      for (int jj = 0; jj < 8; ++jj) bb[jj] = B_s[k * 129 + tx + 16 * jj];
#pragma unroll
      for (int pp = 0; pp < 5; ++pp)
#pragma unroll
        for (int jj = 0; jj < 8; ++jj) acc[pp][jj] += a[pp] * bb[jj];
    }
  }
#pragma unroll
  for (int pp = 0; pp < 5; ++pp) {
    int cm = ty + 16 * pp;
    if (cm >= CM_) continue;
    float sc = scale_arr[inst * CM_ + cm];
#pragma unroll
    for (int jj = 0; jj < 8; ++jj)
      local_out[((size_t)inst * CM_ + cm) * 512 + cc * 128 + tx + 16 * jj] = acc[pp][jj] * sc;
  }
}

// ---------------- K3: k = local@Wk + bk ; v = g@Wv + bv (inst 64) ----------------
// grid (4, 65): x = 64-col tile, y = inst. out tile 80x64.
__global__ __launch_bounds__(256) void k3_kv(
    const float* __restrict__ local_in, const float* __restrict__ g,
    const float* __restrict__ Wk, const float* __restrict__ bk,
    const float* __restrict__ Wv, const float* __restrict__ bv,
    float* __restrict__ k_all) {
  const int cc = blockIdx.x, inst = blockIdx.y;
  const bool isv = (inst == 64);
  const float* W = isv ? Wv : Wk;
  const float* bias = isv ? bv : bk;
  __shared__ float A_s[CMP_ * 33];   // [80][33]
  __shared__ float B_s[32 * 65];     // [32][65]
  const int t = threadIdx.x, tx = t & 15, ty = t >> 4;
  float acc[5][4] = {};
  for (int k0 = 0; k0 < 512; k0 += 32) {
    __syncthreads();
#pragma unroll
    for (int i = 0; i < 10; ++i) {
      int idx = t + (i << 8);
      int cm = idx >> 5, k = idx & 31;
      float val = 0.f;
      if (cm < CM_)
        val = isv ? g[cm * 512 + k0 + k]
                  : local_in[((size_t)inst * CM_ + cm) * 512 + k0 + k];
      A_s[cm * 33 + k] = val;
    }
#pragma unroll
    for (int i = 0; i < 8; ++i) {       // 32x64
      int idx = t + (i << 8);
      int k = idx >> 6, c = idx & 63;
      B_s[k * 65 + c] = W[(k0 + k) * 256 + cc * 64 + c];
    }
    __syncthreads();
#pragma unroll 8
    for (int k = 0; k < 32; ++k) {
      float a[5], bb[4];
#pragma unroll
      for (int pp = 0; pp < 5; ++pp) a[pp] = A_s[(ty + 16 * pp) * 33 + k];
#pragma unroll
      for (int jj = 0; jj < 4; ++jj) bb[jj] = B_s[k * 65 + tx + 16 * jj];
#pragma unroll
      for (int pp = 0; pp < 5; ++pp)
#pragma unroll
        for (int jj = 0; jj < 4; ++jj) acc[pp][jj] += a[pp] * bb[jj];
    }
  }
#pragma unroll
  for (int pp = 0; pp < 5; ++pp) {
    int cm = ty + 16 * pp;
    if (cm >= CM_) continue;
#pragma unroll
    for (int jj = 0; jj < 4; ++jj) {
      int c = cc * 64 + tx + 16 * jj;
      k_all[((size_t)inst * CM_ + cm) * 256 + c] = acc[pp][jj] + bias[c];
    }
  }
}

// ---------------- K3b: Wqk[inst] = Wq @ k[inst]^T  ([512][80], pads=0) ----------------
// grid (8, 64): x = 64-row tile of c, y = inst.
__global__ __launch_bounds__(256) void k3b_wqk(
    const float* __restrict__ Wq, const float* __restrict__ k_all,
    float* __restrict__ Wqk) {
  const int rt = blockIdx.x, inst = blockIdx.y;
  __shared__ float A_s[64 * 33];     // [64][33]
  __shared__ float B_s[32 * 81];     // [32][81]
  const int t = threadIdx.x, tx = t & 15, ty = t >> 4;
  float acc[4][5] = {};
  for (int k0 = 0; k0 < 256; k0 += 32) {
    __syncthreads();
#pragma unroll
    for (int i = 0; i < 8; ++i) {       // Wq chunk 64x32
      int idx = t + (i << 8);
      int r = idx >> 5, k = idx & 31;
      A_s[r * 33 + k] = Wq[(rt * 64 + r) * 256 + k0 + k];
    }
#pragma unroll
    for (int i = 0; i < 10; ++i) {      // k^T chunk 32x80
      int idx = t + (i << 8);
      int k = idx & 31, cm = idx >> 5;
      B_s[k * 81 + cm] = (cm < CM_) ? k_all[((size_t)inst * CM_ + cm) * 256 + k0 + k] : 0.f;
    }
    __syncthreads();
#pragma unroll 8
    for (int k = 0; k < 32; ++k) {
      float a[4], bb[5];
#pragma unroll
      for (int pp = 0; pp < 4; ++pp) a[pp] = A_s[(ty + 16 * pp) * 33 + k];
#pragma unroll
      for (int jj = 0; jj < 5; ++jj) bb[jj] = B_s[k * 81 + tx + 16 * jj];
#pragma unroll
      for (int pp = 0; pp < 4; ++pp)
#pragma unroll
        for (int jj = 0; jj < 5; ++jj) acc[pp][jj] += a[pp] * bb[jj];
    }
  }
#pragma unroll
  for (int pp = 0; pp < 4; ++pp)
#pragma unroll
    for (int jj = 0; jj < 5; ++jj)
      Wqk[(size_t)inst * 40960 + (size_t)(rt * 64 + ty + 16 * pp) * CMP_ + tx + 16 * jj] = acc[pp][jj];
}

// ---------------- K3c: bk2 = bq . k^T (pads = -1e30) ; BN inv/add ----------------
// grid (65), block 256
__global__ __launch_bounds__(256) void k3c_misc(
    const float* __restrict__ bq, const float* __restrict__ k_all,
    const float* __restrict__ gamma, const float* __restrict__ beta,
    const float* __restrict__ mean, const float* __restrict__ var,
    float* __restrict__ bk2, float* __restrict__ inv_arr, float* __restrict__ add_arr) {
  const int inst = blockIdx.x, t = threadIdx.x;
  if (inst < 64) {
    if (t < CMP_) {
      float s = -1e30f;
      if (t < CM_) {
        s = 0.f;
        const float* kr = k_all + ((size_t)inst * CM_ + t) * 256;
        for (int m = 0; m < 256; ++m) s += bq[m] * kr[m];
      }
      bk2[inst * CMP_ + t] = s;
    }
  } else {
#pragma unroll
    for (int i = 0; i < 2; ++i) {
      int c = t + (i << 8);
      float iv = gamma[c] * rsqrtf(var[c] + 1e-5f);
      inv_arr[c] = iv;
      add_arr[c] = beta[c] - mean[c] * iv;
    }
  }
}

// ---------------- K3d: vW = v @ Wc  ([80][512], pad rows = 0) ----------------
// grid (4): 128-col tiles
__global__ __launch_bounds__(256) void k3d_vw(
    const float* __restrict__ k_all, const float* __restrict__ Wc,
    float* __restrict__ vW) {
  const int cc = blockIdx.x;
  __shared__ float A_s[CMP_ * 33];   // [80][33]
  __shared__ float B_s[32 * 129];    // [32][129]
  const int t = threadIdx.x, tx = t & 15, ty = t >> 4;
  const float* v = k_all + (size_t)64 * CM_ * 256;
  float acc[5][8] = {};
  for (int k0 = 0; k0 < 256; k0 += 32) {
    __syncthreads();
#pragma unroll
    for (int i = 0; i < 10; ++i) {
      int idx = t + (i << 8);
      int cm = idx >> 5, k = idx & 31;
      A_s[cm * 33 + k] = (cm < CM_) ? v[cm * 256 + k0 + k] : 0.f;
    }
#pragma unroll
    for (int i = 0; i < 16; ++i) {      // Wc chunk 32x128
      int idx = t + (i << 8);
      int k = idx >> 7, c = idx & 127;
      B_s[k * 129 + c] = Wc[(k0 + k) * 512 + cc * 128 + c];
    }
    __syncthreads();
#pragma unroll 8
    for (int k = 0; k < 32; ++k) {
      float a[5], bb[8];
#pragma unroll
      for (int pp = 0; pp < 5; ++pp) a[pp] = A_s[(ty + 16 * pp) * 33 + k];
#pragma unroll
      for (int jj = 0; jj < 8; ++jj) bb[jj] = B_s[k * 129 + tx + 16 * jj];
#pragma unroll
      for (int pp = 0; pp < 5; ++pp)
#pragma unroll
        for (int jj = 0; jj < 8; ++jj) acc[pp][jj] += a[pp] * bb[jj];
    }
  }
#pragma unroll
  for (int pp = 0; pp < 5; ++pp)
#pragma unroll
    for (int jj = 0; jj < 8; ++jj)
      vW[(ty + 16 * pp) * 512 + cc * 128 + tx + 16 * jj] = acc[pp][jj];
}

// ---------------- K4: fused logits -> softmax -> y (BN+ReLU) ----------------
// grid (16, 64): x = 64-pixel tile, y = inst. block 256.
__global__ __launch_bounds__(256) void k4_attn(
    const float* __restrict__ x, const float* __restrict__ Wqk,
    const float* __restrict__ bk2, const float* __restrict__ vW,
    const float* __restrict__ inv_arr, const float* __restrict__ add_arr,
    float* __restrict__ y) {
  const int pt = blockIdx.x, inst = blockIdx.y;
  const int b = inst >> 4, n = inst & 15, bh = n >> 2, bw = n & 3;
  const int row_base = bh * 32 + pt * 2;
  const int col_base = bw * 32;
  __shared__ __align__(16) float Ls[64 * 81];     // logits/att [64][81]
  __shared__ __align__(16) float Region[10560];   // Xs[64][65]+Ws[64][81] | Vs[80][132]
  float* Xs = Region;
  float* Ws = Region + 4160;
  float* Vs = Region;
  const int t = threadIdx.x, tx = t & 15, ty = t >> 4;

  // ---- Phase 1: logits[64][80] = xs @ Wqk + bk2 ----
  float acc[4][5];
  {
    float binit[5];
#pragma unroll
    for (int jj = 0; jj < 5; ++jj) binit[jj] = bk2[inst * CMP_ + tx + 16 * jj];
#pragma unroll
    for (int pp = 0; pp < 4; ++pp)
#pragma unroll
      for (int jj = 0; jj < 5; ++jj) acc[pp][jj] = binit[jj];
  }
  for (int c0 = 0; c0 < 512; c0 += 64) {
    __syncthreads();
#pragma unroll
    for (int i = 0; i < 16; ++i) {      // Xs 64x64
      int idx = t + (i << 8);
      int p = idx & 63, k = idx >> 6;
      int pix = (row_base + (p >> 5)) * 128 + col_base + (p & 31);
      Xs[p * 65 + k] = x[((size_t)(b * 512 + c0 + k) << 14) + pix];
    }
#pragma unroll
    for (int i = 0; i < 20; ++i) {      // Ws 64x80 (contiguous global chunk)
      int idx = t + (i << 8);
      int k = idx / CMP_, cm = idx % CMP_;
      Ws[k * 81 + cm] = Wqk[(size_t)inst * 40960 + (size_t)(c0 + k) * CMP_ + cm];
    }
    __syncthreads();
#pragma unroll 8
    for (int k = 0; k < 64; ++k) {
      float a[4], bb[5];
#pragma unroll
      for (int pp = 0; pp < 4; ++pp) a[pp] = Xs[(ty + 16 * pp) * 65 + k];
#pragma unroll
      for (int jj = 0; jj < 5; ++jj) bb[jj] = Ws[k * 81 + tx + 16 * jj];
#pragma unroll
      for (int pp = 0; pp < 4; ++pp)
#pragma unroll
        for (int jj = 0; jj < 5; ++jj) acc[pp][jj] += a[pp] * bb[jj];
    }
  }
  __syncthreads();
#pragma unroll
  for (int pp = 0; pp < 4; ++pp)
#pragma unroll
    for (int jj = 0; jj < 5; ++jj)
      Ls[(ty + 16 * pp) * 81 + tx + 16 * jj] = acc[pp][jj];
  __syncthreads();

  // ---- Phase 2: softmax over 76 per pixel row (pads -1e30 -> 0) ----
  if (t < 64) {
    float* row = Ls + t * 81;
    float m = row[0];
    for (int i = 1; i < CM_; ++i) m = fmaxf(m, row[i]);
    float s = 0.f;
    for (int i = 0; i < CM_; ++i) { float e = __expf(row[i] - m); row[i] = e; s += e; }
    float r = 1.f / s;
    for (int i = 0; i < CM_; ++i) row[i] *= r;
    row[76] = row[77] = row[78] = row[79] = 0.f;
  }

  // ---- Phase 3: y[64][512] = att @ vW, BN affine + ReLU ----
  const int txp = t & 31, tyc = t >> 5;
  for (int cc2 = 0; cc2 < 4; ++cc2) {
    __syncthreads();
#pragma unroll
    for (int i = 0; i < 40; ++i) {      // Vs 80x128
      int idx = t + (i << 8);
      int c = idx & 127, cm = idx >> 7;
      Vs[cm * 132 + c] = vW[cm * 512 + cc2 * 128 + c];
    }
    __syncthreads();
    float acc2[2][16];
#pragma unroll
    for (int r2 = 0; r2 < 2; ++r2)
#pragma unroll
      for (int kk = 0; kk < 16; ++kk) acc2[r2][kk] = 0.f;
#pragma unroll 4
    for (int k = 0; k < CMP_; ++k) {
      float a0 = Ls[txp * 81 + k], a1 = Ls[(txp + 32) * 81 + k];
      const float4* vp = (const float4*)(Vs + k * 132 + tyc * 16);
#pragma unroll
      for (int q4 = 0; q4 < 4; ++q4) {
        float4 vv = vp[q4];
        acc2[0][q4 * 4 + 0] += a0 * vv.x; acc2[0][q4 * 4 + 1] += a0 * vv.y;
        acc2[0][q4 * 4 + 2] += a0 * vv.z; acc2[0][q4 * 4 + 3] += a0 * vv.w;
        acc2[1][q4 * 4 + 0] += a1 * vv.x; acc2[1][q4 * 4 + 1] += a1 * vv.y;
        acc2[1][q4 * 4 + 2] += a1 * vv.z; acc2[1][q4 * 4 + 3] += a1 * vv.w;
      }
    }
#pragma unroll
    for (int r2 = 0; r2 < 2; ++r2) {
      int pix = (row_base + r2) * 128 + col_base + txp;
#pragma unroll
      for (int kk = 0; kk < 16; ++kk) {
        int cout = cc2 * 128 + tyc * 16 + kk;
        float val = acc2[r2][kk] * inv_arr[cout] + add_arr[cout];
        y[((size_t)(b * 512 + cout) << 14) + pix] = fmaxf(val, 0.f);
      }
    }
  }
}

// ---------------- host launch ----------------
extern "C" void kernel_launch(void* const* d_in, const int* in_sizes, int n_in,
                              void* d_out, int out_size, void* d_ws, size_t ws_size,
                              hipStream_t stream) {
  (void)in_sizes; (void)n_in; (void)out_size; (void)ws_size;
  const float* x     = (const float*)d_in[0];
  const float* sim   = (const float*)d_in[1];
  const float* g     = (const float*)d_in[2];
  const float* Wq    = (const float*)d_in[3];
  const float* bq    = (const float*)d_in[4];
  const float* Wk    = (const float*)d_in[5];
  const float* bk    = (const float*)d_in[6];
  const float* Wv    = (const float*)d_in[7];
  const float* bv    = (const float*)d_in[8];
  const float* Wc    = (const float*)d_in[9];
  const float* gamma = (const float*)d_in[10];
  const float* beta  = (const float*)d_in[11];
  const float* mean  = (const float*)d_in[12];
  const float* var   = (const float*)d_in[13];
  float* out = (float*)d_out;
  float* ws  = (float*)d_ws;
  float* y   = out;                    // [4][512][128][128]
  float* pcs = out + 33554432;         // [4][76][4][4]

  hipLaunchKernelGGL(k1_stats, dim3(CM_, 64), dim3(256), 0, stream,
                     sim, pcs, ws + OFF_ROWMAX, ws + OFF_SCALE);
  hipLaunchKernelGGL(k2_local, dim3(4, 64), dim3(256), 0, stream,
                     x, sim, ws + OFF_ROWMAX, ws + OFF_SCALE, ws + OFF_LOCAL);
  hipLaunchKernelGGL(k3_kv, dim3(4, 65), dim3(256), 0, stream,
                     ws + OFF_LOCAL, g, Wk, bk, Wv, bv, ws + OFF_KALL);
  hipLaunchKernelGGL(k3b_wqk, dim3(8, 64), dim3(256), 0, stream,
                     Wq, ws + OFF_KALL, ws + OFF_WQK);
  hipLaunchKernelGGL(k3c_misc, dim3(65), dim3(256), 0, stream,
                     bq, ws + OFF_KALL, gamma, beta, mean, var,
                     ws + OFF_BK2, ws + OFF_INV, ws + OFF_ADD);
  hipLaunchKernelGGL(k3d_vw, dim3(4), dim3(256), 0, stream,
                     ws + OFF_KALL, Wc, ws + OFF_VW);
  hipLaunchKernelGGL(k4_attn, dim3(16, 64), dim3(256), 0, stream,
                     x, ws + OFF_WQK, ws + OFF_BK2, ws + OFF_VW,
                     ws + OFF_INV, ws + OFF_ADD, y);
}

// Round 2
// 597.276 us; speedup vs baseline: 1.4513x; 1.4513x over previous
//
#include <hip/hip_runtime.h>

// ---------------- problem constants ----------------
// b=4, C=512, h=w=128, BH=BW=4 -> 64 instances, P=1024 pixels each
// CM=76 (pad 80/96), mid=256
#define CM_    76
#define CMP_   80

typedef __attribute__((ext_vector_type(4))) float f32x4;
typedef __attribute__((ext_vector_type(8))) short bf16x8;

__device__ __forceinline__ unsigned short f2bf(float f) {
  union { float f; unsigned u; } v; v.f = f;
  unsigned r = v.u + 0x7FFFu + ((v.u >> 16) & 1u);
  return (unsigned short)(r >> 16);
}
__device__ __forceinline__ unsigned pack2(float a, float b) {
  return (unsigned)f2bf(a) | ((unsigned)f2bf(b) << 16);
}

// ---------------- workspace layout (float offsets) ----------------
#define OFF_ROWMAX 0            // [64][76]
#define OFF_SCALE  4864         // [64][76]  conf/sumexp
#define OFF_LOCAL  9728         // [64][76][512] fp32
#define OFF_KALL   2500096      // [65][76][256] fp32 (inst 64 = v)
#define OFF_BK2    3764736      // [64][80] fp32 (pads -1e30)
#define OFF_INV    3769856      // [512]
#define OFF_ADD    3770368      // [512]
#define OFF_WQKT   3770880      // [64][80][512] bf16 (ushort region)
#define OFF_VWT    5081600      // [512][96] bf16
// total ~5.11M floats = 20.4 MB

// ---------------- K1: pooling + softmax stats (unchanged) ----------------
__global__ __launch_bounds__(256) void k1_stats(
    const float* __restrict__ sim, float* __restrict__ pcs,
    float* __restrict__ rowmax, float* __restrict__ scale_arr) {
  const int cm = blockIdx.x, inst = blockIdx.y;
  const int b = inst >> 4, n = inst & 15, bh = n >> 2, bw = n & 3;
  const float* base = sim + ((size_t)(b * CM_ + cm) << 14);
  const int t = threadIdx.x;
  float v[4];
  float lsum = 0.f, lmax = -1e30f;
#pragma unroll
  for (int i = 0; i < 4; ++i) {
    int p = t + (i << 8);
    int pix = ((bh * 32 + (p >> 5)) << 7) + bw * 32 + (p & 31);
    float xv = base[pix];
    v[i] = xv; lsum += xv; lmax = fmaxf(lmax, xv);
  }
#pragma unroll
  for (int off = 32; off; off >>= 1) {
    lsum += __shfl_down(lsum, off);
    lmax = fmaxf(lmax, __shfl_down(lmax, off));
  }
  __shared__ float ssum[4], smax[4], bc[2];
  const int wid = t >> 6;
  if ((t & 63) == 0) { ssum[wid] = lsum; smax[wid] = lmax; }
  __syncthreads();
  if (t == 0) {
    bc[0] = ssum[0] + ssum[1] + ssum[2] + ssum[3];
    bc[1] = fmaxf(fmaxf(smax[0], smax[1]), fmaxf(smax[2], smax[3]));
  }
  __syncthreads();
  const float M = bc[1];
  float le = 0.f;
#pragma unroll
  for (int i = 0; i < 4; ++i) le += __expf(v[i] - M);
#pragma unroll
  for (int off = 32; off; off >>= 1) le += __shfl_down(le, off);
  if ((t & 63) == 0) ssum[wid] = le;
  __syncthreads();
  if (t == 0) {
    float E = ssum[0] + ssum[1] + ssum[2] + ssum[3];
    float conf = bc[0] * (1.f / 1024.f);
    pcs[((b * CM_ + cm) << 4) + n] = conf;
    rowmax[inst * CM_ + cm] = M;
    scale_arr[inst * CM_ + cm] = conf / E;
  }
}

// ---------------- K2 (MFMA): local[cm][ch] = sum_px (scale*exp(sim)) * x ----------------
// grid (8, 64): cc = 64-ch block, inst. 4 waves each own 16 ch; A (exp weights) shared in LDS.
__global__ __launch_bounds__(256) void k2_local(
    const float* __restrict__ x, const float* __restrict__ sim,
    const float* __restrict__ rowmax, const float* __restrict__ scale_arr,
    float* __restrict__ local_out) {
  const int cc = blockIdx.x, inst = blockIdx.y;
  const int b = inst >> 4, n = inst & 15, bh = n >> 2, bw = n & 3;
  __shared__ unsigned short As[CMP_ * 136];   // [80][px 128 pad 136] bf16
  const int t = threadIdx.x, lane = t & 63, w = t >> 6;
  const int lo = lane & 15, hi = lane >> 4;
  const int chw = cc * 64 + w * 16;           // wave's 16-ch column tile
  const int cm0 = t >> 3, pq = t & 7;         // staging roles

  f32x4 acc[5];
#pragma unroll
  for (int T = 0; T < 5; ++T) acc[T] = (f32x4){0.f, 0.f, 0.f, 0.f};

  for (int pc = 0; pc < 8; ++pc) {            // 128-px chunks
    __syncthreads();
    // stage A: [80][128] bf16 = scale*exp(sim - rowmax); pad rows zero
#pragma unroll
    for (int j = 0; j < 3; ++j) {
      int cm = cm0 + 32 * j;
      if (cm < CMP_) {
        if (cm < CM_) {
          float rm = rowmax[inst * CM_ + cm];
          float sc = scale_arr[inst * CM_ + cm];
          const float* srow = sim + ((size_t)(b * CM_ + cm) << 14);
#pragma unroll
          for (int i = 0; i < 4; ++i) {
            int pxl = i * 32 + pq * 4;
            int gpx = pc * 128 + pxl;
            int pix = ((bh * 32 + (gpx >> 5)) << 7) + bw * 32 + (gpx & 31);
            float4 vv = *(const float4*)(srow + pix);
            unsigned l32 = pack2(sc * __expf(vv.x - rm), sc * __expf(vv.y - rm));
            unsigned h32 = pack2(sc * __expf(vv.z - rm), sc * __expf(vv.w - rm));
            *(unsigned long long*)(&As[cm * 136 + pxl]) =
                (unsigned long long)l32 | ((unsigned long long)h32 << 32);
          }
        } else {
#pragma unroll
          for (int i = 0; i < 4; ++i)
            *(unsigned long long*)(&As[cm * 136 + i * 32 + pq * 4]) = 0ull;
        }
      }
    }
    __syncthreads();
    // 4 k-steps of 32 px
#pragma unroll
    for (int ks = 0; ks < 4; ++ks) {
      int gpx0 = pc * 128 + ks * 32 + hi * 8;
      int pix0 = ((bh * 32 + (gpx0 >> 5)) << 7) + bw * 32 + (gpx0 & 31);
      const float* xr = x + (((size_t)(b * 512 + chw + lo)) << 14) + pix0;
      float4 v0 = *(const float4*)(xr);
      float4 v1 = *(const float4*)(xr + 4);
      bf16x8 bfr;
      ((unsigned*)&bfr)[0] = pack2(v0.x, v0.y);
      ((unsigned*)&bfr)[1] = pack2(v0.z, v0.w);
      ((unsigned*)&bfr)[2] = pack2(v1.x, v1.y);
      ((unsigned*)&bfr)[3] = pack2(v1.z, v1.w);
#pragma unroll
      for (int T = 0; T < 5; ++T) {
        bf16x8 afr = *(bf16x8*)(&As[(T * 16 + lo) * 136 + ks * 32 + hi * 8]);
        acc[T] = __builtin_amdgcn_mfma_f32_16x16x32_bf16(afr, bfr, acc[T], 0, 0, 0);
      }
    }
  }
  // epilogue: D col=ch(lo), row=cm
#pragma unroll
  for (int T = 0; T < 5; ++T)
#pragma unroll
    for (int r = 0; r < 4; ++r) {
      int cm = T * 16 + hi * 4 + r;
      if (cm < CM_)
        local_out[((size_t)inst * CM_ + cm) * 512 + chw + lo] = acc[T][r];
    }
}

// ---------------- K3: k = local@Wk + bk ; v = g@Wv + bv (fp32, unchanged) ----------------
__global__ __launch_bounds__(256) void k3_kv(
    const float* __restrict__ local_in, const float* __restrict__ g,
    const float* __restrict__ Wk, const float* __restrict__ bk,
    const float* __restrict__ Wv, const float* __restrict__ bv,
    float* __restrict__ k_all) {
  const int cc = blockIdx.x, inst = blockIdx.y;
  const bool isv = (inst == 64);
  const float* W = isv ? Wv : Wk;
  const float* bias = isv ? bv : bk;
  __shared__ float A_s[CMP_ * 33];
  __shared__ float B_s[32 * 65];
  const int t = threadIdx.x, tx = t & 15, ty = t >> 4;
  float acc[5][4] = {};
  for (int k0 = 0; k0 < 512; k0 += 32) {
    __syncthreads();
#pragma unroll
    for (int i = 0; i < 10; ++i) {
      int idx = t + (i << 8);
      int cm = idx >> 5, k = idx & 31;
      float val = 0.f;
      if (cm < CM_)
        val = isv ? g[cm * 512 + k0 + k]
                  : local_in[((size_t)inst * CM_ + cm) * 512 + k0 + k];
      A_s[cm * 33 + k] = val;
    }
#pragma unroll
    for (int i = 0; i < 8; ++i) {
      int idx = t + (i << 8);
      int k = idx >> 6, c = idx & 63;
      B_s[k * 65 + c] = W[(k0 + k) * 256 + cc * 64 + c];
    }
    __syncthreads();
#pragma unroll 8
    for (int k = 0; k < 32; ++k) {
      float a[5], bb[4];
#pragma unroll
      for (int pp = 0; pp < 5; ++pp) a[pp] = A_s[(ty + 16 * pp) * 33 + k];
#pragma unroll
      for (int jj = 0; jj < 4; ++jj) bb[jj] = B_s[k * 65 + tx + 16 * jj];
#pragma unroll
      for (int pp = 0; pp < 5; ++pp)
#pragma unroll
        for (int jj = 0; jj < 4; ++jj) acc[pp][jj] += a[pp] * bb[jj];
    }
  }
#pragma unroll
  for (int pp = 0; pp < 5; ++pp) {
    int cm = ty + 16 * pp;
    if (cm >= CM_) continue;
#pragma unroll
    for (int jj = 0; jj < 4; ++jj) {
      int c = cc * 64 + tx + 16 * jj;
      k_all[((size_t)inst * CM_ + cm) * 256 + c] = acc[pp][jj] + bias[c];
    }
  }
}

// ---------------- K3b: Wqkt[inst][cm][c] = (Wq @ k^T)^T  bf16, pads(cm 76-79)=0 ----------------
__global__ __launch_bounds__(256) void k3b_wqk(
    const float* __restrict__ Wq, const float* __restrict__ k_all,
    unsigned short* __restrict__ Wqkt) {
  const int rt = blockIdx.x, inst = blockIdx.y;
  __shared__ float A_s[64 * 33];
  __shared__ float B_s[32 * 81];
  const int t = threadIdx.x, tx = t & 15, ty = t >> 4;
  float acc[4][5] = {};
  for (int k0 = 0; k0 < 256; k0 += 32) {
    __syncthreads();
#pragma unroll
    for (int i = 0; i < 8; ++i) {
      int idx = t + (i << 8);
      int r = idx >> 5, k = idx & 31;
      A_s[r * 33 + k] = Wq[(rt * 64 + r) * 256 + k0 + k];
    }
#pragma unroll
    for (int i = 0; i < 10; ++i) {
      int idx = t + (i << 8);
      int k = idx & 31, cm = idx >> 5;
      B_s[k * 81 + cm] = (cm < CM_) ? k_all[((size_t)inst * CM_ + cm) * 256 + k0 + k] : 0.f;
    }
    __syncthreads();
#pragma unroll 8
    for (int k = 0; k < 32; ++k) {
      float a[4], bb[5];
#pragma unroll
      for (int pp = 0; pp < 4; ++pp) a[pp] = A_s[(ty + 16 * pp) * 33 + k];
#pragma unroll
      for (int jj = 0; jj < 5; ++jj) bb[jj] = B_s[k * 81 + tx + 16 * jj];
#pragma unroll
      for (int pp = 0; pp < 4; ++pp)
#pragma unroll
        for (int jj = 0; jj < 5; ++jj) acc[pp][jj] += a[pp] * bb[jj];
    }
  }
#pragma unroll
  for (int pp = 0; pp < 4; ++pp)
#pragma unroll
    for (int jj = 0; jj < 5; ++jj) {
      int cm = tx + 16 * jj, c = rt * 64 + ty + 16 * pp;
      Wqkt[(size_t)inst * 40960 + (size_t)cm * 512 + c] = f2bf(acc[pp][jj]);
    }
}

// ---------------- K3c: bk2 = bq.k^T (pads -1e30) ; BN inv/add ----------------
__global__ __launch_bounds__(256) void k3c_misc(
    const float* __restrict__ bq, const float* __restrict__ k_all,
    const float* __restrict__ gamma, const float* __restrict__ beta,
    const float* __restrict__ mean, const float* __restrict__ var,
    float* __restrict__ bk2, float* __restrict__ inv_arr, float* __restrict__ add_arr) {
  const int inst = blockIdx.x, t = threadIdx.x;
  if (inst < 64) {
    if (t < CMP_) {
      float s = -1e30f;
      if (t < CM_) {
        s = 0.f;
        const float* kr = k_all + ((size_t)inst * CM_ + t) * 256;
        for (int m = 0; m < 256; ++m) s += bq[m] * kr[m];
      }
      bk2[inst * CMP_ + t] = s;
    }
  } else {
#pragma unroll
    for (int i = 0; i < 2; ++i) {
      int c = t + (i << 8);
      float iv = gamma[c] * rsqrtf(var[c] + 1e-5f);
      inv_arr[c] = iv;
      add_arr[c] = beta[c] - mean[c] * iv;
    }
  }
}

// ---------------- K3d: vWt[c][cm] = (v @ Wc)^T bf16, [512][96], pads zero ----------------
// grid (16): 32-col tiles
__global__ __launch_bounds__(256) void k3d_vw(
    const float* __restrict__ k_all, const float* __restrict__ Wc,
    unsigned short* __restrict__ vWt) {
  const int cc = blockIdx.x;
  __shared__ float A_s[CMP_ * 33];
  __shared__ float B_s[32 * 33];
  const int t = threadIdx.x, tx = t & 15, ty = t >> 4;
  const float* v = k_all + (size_t)64 * CM_ * 256;
  float acc[5][2] = {};
  for (int k0 = 0; k0 < 256; k0 += 32) {
    __syncthreads();
#pragma unroll
    for (int i = 0; i < 10; ++i) {
      int idx = t + (i << 8);
      int cm = idx >> 5, k = idx & 31;
      A_s[cm * 33 + k] = (cm < CM_) ? v[cm * 256 + k0 + k] : 0.f;
    }
#pragma unroll
    for (int i2 = 0; i2 < 4; ++i2) {
      int k = (t >> 5) + i2 * 8, c = t & 31;
      B_s[k * 33 + c] = Wc[(k0 + k) * 512 + cc * 32 + c];
    }
    __syncthreads();
#pragma unroll 8
    for (int k = 0; k < 32; ++k) {
      float a[5], bb[2];
#pragma unroll
      for (int pp = 0; pp < 5; ++pp) a[pp] = A_s[(ty + 16 * pp) * 33 + k];
#pragma unroll
      for (int jj = 0; jj < 2; ++jj) bb[jj] = B_s[k * 33 + tx + 16 * jj];
#pragma unroll
      for (int pp = 0; pp < 5; ++pp)
#pragma unroll
        for (int jj = 0; jj < 2; ++jj) acc[pp][jj] += a[pp] * bb[jj];
    }
  }
#pragma unroll
  for (int pp = 0; pp < 5; ++pp)
#pragma unroll
    for (int jj = 0; jj < 2; ++jj) {
      int c = cc * 32 + tx + 16 * jj;
      vWt[(size_t)c * 96 + ty + 16 * pp] = f2bf(acc[pp][jj]);
    }
  // zero k-pads 80..95
  {
    int cl = t >> 3, pk = 80 + (t & 7) * 2;
    *(unsigned*)(&vWt[(size_t)(cc * 32 + cl) * 96 + pk]) = 0u;
  }
}

// ---------------- K4 (MFMA): logits -> in-register softmax -> y (BN+ReLU) ----------------
// grid (8, 64): pt = 128-px tile, inst. Each wave owns one 32-px image row.
__global__ __launch_bounds__(256) void k4_attn(
    const float* __restrict__ x, const unsigned short* __restrict__ Wqkt,
    const float* __restrict__ bk2, const unsigned short* __restrict__ vWt,
    const float* __restrict__ inv_arr, const float* __restrict__ add_arr,
    float* __restrict__ y) {
  const int pt = blockIdx.x, inst = blockIdx.y;
  const int b = inst >> 4, n = inst & 15, bh = n >> 2, bw = n & 3;
  __shared__ unsigned short Xs[4][32 * 72];   // per-wave [32 px][64 ch pad 72] bf16
  __shared__ unsigned short Att[4][32 * 96];  // per-wave [32 px][96] bf16
  __shared__ float bn_s[1024];                // inv | add
  const int t = threadIdx.x, lane = t & 63, w = t >> 6;
  const int lo = lane & 15, hi = lane >> 4;
  const int pq = lane & 7, chp0 = lane >> 3;

  for (int i = t; i < 512; i += 256) { bn_s[i] = inv_arr[i]; bn_s[512 + i] = add_arr[i]; }

  const int imgrow = bh * 32 + pt * 4 + w;    // wave's single image row
  const size_t pixbase = (size_t)imgrow * 128 + bw * 32;
  const size_t xrowbase = (((size_t)b * 512) << 14) + pixbase;
  const unsigned short* Wi = Wqkt + (size_t)inst * 40960;

  // ---- Phase 1: logits(2 px-tiles x 5 cm-tiles), acc init = bk2 (pads -1e30) ----
  f32x4 acc[2][5];
#pragma unroll
  for (int T = 0; T < 5; ++T) {
    f32x4 bv;
#pragma unroll
    for (int r = 0; r < 4; ++r) bv[r] = bk2[inst * CMP_ + T * 16 + hi * 4 + r];
    acc[0][T] = bv; acc[1][T] = bv;
  }

  for (int kc = 0; kc < 8; ++kc) {            // 64-ch chunks
    // wave-local staging: 32 px x 64 ch, transposed to [px][ch]
#pragma unroll
    for (int i = 0; i < 4; ++i) {
      int chp = chp0 + i * 8;
      int ch = kc * 64 + chp * 2;
      const float* xa = x + xrowbase + ((size_t)ch << 14) + pq * 4;
      float4 va = *(const float4*)(xa);
      float4 vb = *(const float4*)(xa + 16384);
      unsigned short* dst = &Xs[w][(pq * 4) * 72 + chp * 2];
      *(unsigned*)(dst + 0 * 72) = pack2(va.x, vb.x);
      *(unsigned*)(dst + 1 * 72) = pack2(va.y, vb.y);
      *(unsigned*)(dst + 2 * 72) = pack2(va.z, vb.z);
      *(unsigned*)(dst + 3 * 72) = pack2(va.w, vb.w);
    }
#pragma unroll
    for (int ks = 0; ks < 2; ++ks) {
      int kb = kc * 64 + ks * 32 + hi * 8;
      bf16x8 b0 = *(bf16x8*)(&Xs[w][lo * 72 + ks * 32 + hi * 8]);
      bf16x8 b1 = *(bf16x8*)(&Xs[w][(16 + lo) * 72 + ks * 32 + hi * 8]);
#pragma unroll
      for (int T = 0; T < 5; ++T) {
        bf16x8 afr = *(const bf16x8*)(Wi + (size_t)(T * 16 + lo) * 512 + kb);
        acc[0][T] = __builtin_amdgcn_mfma_f32_16x16x32_bf16(afr, b0, acc[0][T], 0, 0, 0);
        acc[1][T] = __builtin_amdgcn_mfma_f32_16x16x32_bf16(afr, b1, acc[1][T], 0, 0, 0);
      }
    }
  }

  // ---- Phase 2: in-register softmax over cm (76 real; pads exp->0), write Att bf16 ----
#pragma unroll
  for (int p = 0; p < 2; ++p) {
    float m = -1e30f;
#pragma unroll
    for (int T = 0; T < 5; ++T)
#pragma unroll
      for (int r = 0; r < 4; ++r) m = fmaxf(m, acc[p][T][r]);
    m = fmaxf(m, __shfl_xor(m, 16));
    m = fmaxf(m, __shfl_xor(m, 32));
    float e[5][4];
    float s = 0.f;
#pragma unroll
    for (int T = 0; T < 5; ++T)
#pragma unroll
      for (int r = 0; r < 4; ++r) { float ev = __expf(acc[p][T][r] - m); e[T][r] = ev; s += ev; }
    s += __shfl_xor(s, 16);
    s += __shfl_xor(s, 32);
    float rinv = 1.f / s;
    int px = p * 16 + lo;
#pragma unroll
    for (int T = 0; T < 5; ++T) {
      unsigned l32 = pack2(e[T][0] * rinv, e[T][1] * rinv);
      unsigned h32 = pack2(e[T][2] * rinv, e[T][3] * rinv);
      *(unsigned long long*)(&Att[w][px * 96 + T * 16 + hi * 4]) =
          (unsigned long long)l32 | ((unsigned long long)h32 << 32);
    }
    *(unsigned long long*)(&Att[w][px * 96 + 80 + hi * 4]) = 0ull;
  }

  __syncthreads();  // bn_s visibility (Att is wave-local)

  // ---- Phase 3: y^T[ch][px] = vWt @ Att^T, BN + ReLU, coalesced stores ----
  bf16x8 bfr3[2][3];
#pragma unroll
  for (int p = 0; p < 2; ++p)
#pragma unroll
    for (int ks = 0; ks < 3; ++ks)
      bfr3[p][ks] = *(bf16x8*)(&Att[w][(p * 16 + lo) * 96 + ks * 32 + hi * 8]);

  for (int cT = 0; cT < 32; ++cT) {
    f32x4 a0 = (f32x4){0.f, 0.f, 0.f, 0.f}, a1 = a0;
    const unsigned short* vr = vWt + (size_t)(cT * 16 + lo) * 96;
#pragma unroll
    for (int ks = 0; ks < 3; ++ks) {
      bf16x8 afr = *(const bf16x8*)(vr + ks * 32 + hi * 8);
      a0 = __builtin_amdgcn_mfma_f32_16x16x32_bf16(afr, bfr3[0][ks], a0, 0, 0, 0);
      a1 = __builtin_amdgcn_mfma_f32_16x16x32_bf16(afr, bfr3[1][ks], a1, 0, 0, 0);
    }
    f32x4 inv4 = *(f32x4*)(&bn_s[cT * 16 + hi * 4]);
    f32x4 add4 = *(f32x4*)(&bn_s[512 + cT * 16 + hi * 4]);
#pragma unroll
    for (int r = 0; r < 4; ++r) {
      int ch = cT * 16 + hi * 4 + r;
      float v0 = fmaxf(a0[r] * inv4[r] + add4[r], 0.f);
      float v1 = fmaxf(a1[r] * inv4[r] + add4[r], 0.f);
      size_t yb = (((size_t)(b * 512 + ch)) << 14) + pixbase;
      y[yb + lo] = v0;
      y[yb + 16 + lo] = v1;
    }
  }
}

// ---------------- host launch ----------------
extern "C" void kernel_launch(void* const* d_in, const int* in_sizes, int n_in,
                              void* d_out, int out_size, void* d_ws, size_t ws_size,
                              hipStream_t stream) {
  (void)in_sizes; (void)n_in; (void)out_size; (void)ws_size;
  const float* x     = (const float*)d_in[0];
  const float* sim   = (const float*)d_in[1];
  const float* g     = (const float*)d_in[2];
  const float* Wq    = (const float*)d_in[3];
  const float* bq    = (const float*)d_in[4];
  const float* Wk    = (const float*)d_in[5];
  const float* bk    = (const float*)d_in[6];
  const float* Wv    = (const float*)d_in[7];
  const float* bv    = (const float*)d_in[8];
  const float* Wc    = (const float*)d_in[9];
  const float* gamma = (const float*)d_in[10];
  const float* beta  = (const float*)d_in[11];
  const float* mean  = (const float*)d_in[12];
  const float* var   = (const float*)d_in[13];
  float* out = (float*)d_out;
  float* ws  = (float*)d_ws;
  float* y   = out;                    // [4][512][128][128]
  float* pcs = out + 33554432;         // [4][76][4][4]
  unsigned short* Wqkt = (unsigned short*)(ws + OFF_WQKT);
  unsigned short* vWt  = (unsigned short*)(ws + OFF_VWT);

  hipLaunchKernelGGL(k1_stats, dim3(CM_, 64), dim3(256), 0, stream,
                     sim, pcs, ws + OFF_ROWMAX, ws + OFF_SCALE);
  hipLaunchKernelGGL(k2_local, dim3(8, 64), dim3(256), 0, stream,
                     x, sim, ws + OFF_ROWMAX, ws + OFF_SCALE, ws + OFF_LOCAL);
  hipLaunchKernelGGL(k3_kv, dim3(4, 65), dim3(256), 0, stream,
                     ws + OFF_LOCAL, g, Wk, bk, Wv, bv, ws + OFF_KALL);
  hipLaunchKernelGGL(k3b_wqk, dim3(8, 64), dim3(256), 0, stream,
                     Wq, ws + OFF_KALL, Wqkt);
  hipLaunchKernelGGL(k3c_misc, dim3(65), dim3(256), 0, stream,
                     bq, ws + OFF_KALL, gamma, beta, mean, var,
                     ws + OFF_BK2, ws + OFF_INV, ws + OFF_ADD);
  hipLaunchKernelGGL(k3d_vw, dim3(16), dim3(256), 0, stream,
                     ws + OFF_KALL, Wc, vWt);
  hipLaunchKernelGGL(k4_attn, dim3(8, 64), dim3(256), 0, stream,
                     x, Wqkt, ws + OFF_BK2, vWt,
                     ws + OFF_INV, ws + OFF_ADD, y);
}

// Round 3
// 430.846 us; speedup vs baseline: 2.0119x; 1.3863x over previous
//
#include <hip/hip_runtime.h>

// ---------------- problem constants ----------------
// b=4, C=512, h=w=128, BH=BW=4 -> 64 instances, P=1024 pixels each
// CM=76 (pad 80/96), mid=256
#define CM_    76
#define CMP_   80

typedef __attribute__((ext_vector_type(4))) float f32x4;
typedef __attribute__((ext_vector_type(8))) short bf16x8;

__device__ __forceinline__ unsigned short f2bf(float f) {
  union { float f; unsigned u; } v; v.f = f;
  unsigned r = v.u + 0x7FFFu + ((v.u >> 16) & 1u);
  return (unsigned short)(r >> 16);
}
__device__ __forceinline__ unsigned pack2(float a, float b) {
  return (unsigned)f2bf(a) | ((unsigned)f2bf(b) << 16);
}
__device__ __forceinline__ float bf2f(unsigned short u) {
  union { unsigned u; float f; } v; v.u = ((unsigned)u) << 16; return v.f;
}

// ---------------- workspace layout (float offsets; all 16B-aligned) ----------------
#define OFF_ROWMAX  0            // [64][76] f32
#define OFF_SCALE   4864         // [64][76] f32
#define OFF_BK2     9728         // [64][80] f32 (pads -1e30)
#define OFF_INV     14848        // [512] f32
#define OFF_ADD     15360        // [512] f32
#define OFF_WKBQ    15872        // [512] f32  (Wk@bq)
#define OFF_BQKADD  16384        // [512] f32  (Wq@bk)
#define OFF_CBB     16896        // [1] f32    (bq.bk)
#define OFF_LOCALBF 16900        // [64][80][512] bf16
#define OFF_WQKT    1327620      // [64][80][512] bf16
#define OFF_VWT     2638340      // [512][96] bf16
#define OFF_WQWKT   2662916      // [512][512] bf16 (Wq@Wk^T)
#define OFF_WVWCT   2793988      // [512][512] bf16 (Wc^T@Wv^T : [c2][c])
// total 2,925,060 floats = 11.7 MB

// ---------------- kW (one-off): WqWkT / WvWcT, 512x512 bf16, K=256 ----------------
// grid (64, 2): blk.x -> 64x64 tile, blk.y = sel (0: Wq@Wk^T, 1: Wc^T@Wv^T)
__global__ __launch_bounds__(256) void kW_pre(
    const float* __restrict__ Wq, const float* __restrict__ Wk,
    const float* __restrict__ Wv, const float* __restrict__ Wc,
    unsigned short* __restrict__ WqWkT, unsigned short* __restrict__ WvWcT) {
  const int r0 = (blockIdx.x >> 3) * 64, c0 = (blockIdx.x & 7) * 64;
  const int sel = blockIdx.y;
  __shared__ __align__(16) unsigned short Asm[64 * 40];
  __shared__ __align__(16) unsigned short Bsm[64 * 40];
  const int t = threadIdx.x, lane = t & 63, w = t >> 6;
  const int lo = lane & 15, hi = lane >> 4;
  f32x4 acc[4];
#pragma unroll
  for (int cT = 0; cT < 4; ++cT) acc[cT] = (f32x4){0.f, 0.f, 0.f, 0.f};
  const float* Bsrc = sel ? Wv : Wk;
  for (int kc = 0; kc < 8; ++kc) {
    const int k0 = kc * 32;
    __syncthreads();
    // B: [n][m] from Bsrc[(c0+n)*256 + k0+m]
    {
      int n = t >> 2, mq = (t & 3) * 8;
      const float* src = Bsrc + (size_t)(c0 + n) * 256 + k0 + mq;
      float4 v0 = *(const float4*)src, v1 = *(const float4*)(src + 4);
      unsigned* d = (unsigned*)&Bsm[n * 40 + mq];
      d[0] = pack2(v0.x, v0.y); d[1] = pack2(v0.z, v0.w);
      d[2] = pack2(v1.x, v1.y); d[3] = pack2(v1.z, v1.w);
    }
    if (sel == 0) {   // A: Wq rows
      int r = t >> 2, mq = (t & 3) * 8;
      const float* src = Wq + (size_t)(r0 + r) * 256 + k0 + mq;
      float4 v0 = *(const float4*)src, v1 = *(const float4*)(src + 4);
      unsigned* d = (unsigned*)&Asm[r * 40 + mq];
      d[0] = pack2(v0.x, v0.y); d[1] = pack2(v0.z, v0.w);
      d[2] = pack2(v1.x, v1.y); d[3] = pack2(v1.z, v1.w);
    } else {          // A: Wc^T (transpose in LDS)
      int m = t >> 3, c2q = (t & 7) * 8;
      const float* src = Wc + (size_t)(k0 + m) * 512 + r0 + c2q;
      float4 v0 = *(const float4*)src, v1 = *(const float4*)(src + 4);
      Asm[(c2q + 0) * 40 + m] = f2bf(v0.x); Asm[(c2q + 1) * 40 + m] = f2bf(v0.y);
      Asm[(c2q + 2) * 40 + m] = f2bf(v0.z); Asm[(c2q + 3) * 40 + m] = f2bf(v0.w);
      Asm[(c2q + 4) * 40 + m] = f2bf(v1.x); Asm[(c2q + 5) * 40 + m] = f2bf(v1.y);
      Asm[(c2q + 6) * 40 + m] = f2bf(v1.z); Asm[(c2q + 7) * 40 + m] = f2bf(v1.w);
    }
    __syncthreads();
    bf16x8 afr = *(bf16x8*)(&Asm[(w * 16 + lo) * 40 + hi * 8]);
#pragma unroll
    for (int cT = 0; cT < 4; ++cT) {
      bf16x8 bfr = *(bf16x8*)(&Bsm[(cT * 16 + lo) * 40 + hi * 8]);
      acc[cT] = __builtin_amdgcn_mfma_f32_16x16x32_bf16(afr, bfr, acc[cT], 0, 0, 0);
    }
  }
  unsigned short* dst = sel ? WvWcT : WqWkT;
#pragma unroll
  for (int cT = 0; cT < 4; ++cT)
#pragma unroll
    for (int rr = 0; rr < 4; ++rr)
      dst[(size_t)(r0 + w * 16 + hi * 4 + rr) * 512 + c0 + cT * 16 + lo] = f2bf(acc[cT][rr]);
}

// ---------------- kB (one-off): wkbq, bqkadd, cbb, BN inv/add ----------------
// grid (2), 256 thr
__global__ __launch_bounds__(256) void kB_pre(
    const float* __restrict__ Wk, const float* __restrict__ Wq,
    const float* __restrict__ bq, const float* __restrict__ bk,
    const float* __restrict__ gamma, const float* __restrict__ beta,
    const float* __restrict__ mean, const float* __restrict__ var,
    float* __restrict__ wkbq, float* __restrict__ bqkadd,
    float* __restrict__ invp, float* __restrict__ addp, float* __restrict__ cbbp) {
  const int c = blockIdx.x * 256 + threadIdx.x;
  const float* wkr = Wk + (size_t)c * 256;
  const float* wqr = Wq + (size_t)c * 256;
  float s1 = 0.f, s2 = 0.f;
  for (int m = 0; m < 256; ++m) { s1 += wkr[m] * bq[m]; s2 += wqr[m] * bk[m]; }
  wkbq[c] = s1; bqkadd[c] = s2;
  float iv = gamma[c] * rsqrtf(var[c] + 1e-5f);
  invp[c] = iv; addp[c] = beta[c] - mean[c] * iv;
  if (c == 0) {
    float s = 0.f;
    for (int m = 0; m < 256; ++m) s += bq[m] * bk[m];
    cbbp[0] = s;
  }
}

// ---------------- K1: pooling + softmax stats ----------------
__global__ __launch_bounds__(256) void k1_stats(
    const float* __restrict__ sim, float* __restrict__ pcs,
    float* __restrict__ rowmax, float* __restrict__ scale_arr) {
  const int cm = blockIdx.x, inst = blockIdx.y;
  const int b = inst >> 4, n = inst & 15, bh = n >> 2, bw = n & 3;
  const float* base = sim + ((size_t)(b * CM_ + cm) << 14);
  const int t = threadIdx.x;
  float v[4];
  float lsum = 0.f, lmax = -1e30f;
#pragma unroll
  for (int i = 0; i < 4; ++i) {
    int p = t + (i << 8);
    int pix = ((bh * 32 + (p >> 5)) << 7) + bw * 32 + (p & 31);
    float xv = base[pix];
    v[i] = xv; lsum += xv; lmax = fmaxf(lmax, xv);
  }
#pragma unroll
  for (int off = 32; off; off >>= 1) {
    lsum += __shfl_down(lsum, off);
    lmax = fmaxf(lmax, __shfl_down(lmax, off));
  }
  __shared__ float ssum[4], smax[4], bc[2];
  const int wid = t >> 6;
  if ((t & 63) == 0) { ssum[wid] = lsum; smax[wid] = lmax; }
  __syncthreads();
  if (t == 0) {
    bc[0] = ssum[0] + ssum[1] + ssum[2] + ssum[3];
    bc[1] = fmaxf(fmaxf(smax[0], smax[1]), fmaxf(smax[2], smax[3]));
  }
  __syncthreads();
  const float M = bc[1];
  float le = 0.f;
#pragma unroll
  for (int i = 0; i < 4; ++i) le += __expf(v[i] - M);
#pragma unroll
  for (int off = 32; off; off >>= 1) le += __shfl_down(le, off);
  if ((t & 63) == 0) ssum[wid] = le;
  __syncthreads();
  if (t == 0) {
    float E = ssum[0] + ssum[1] + ssum[2] + ssum[3];
    float conf = bc[0] * (1.f / 1024.f);
    pcs[((b * CM_ + cm) << 4) + n] = conf;
    rowmax[inst * CM_ + cm] = M;
    scale_arr[inst * CM_ + cm] = conf / E;
  }
}

// ---------------- K2 (MFMA): local[cm][ch] bf16 = sum_px (scale*exp(sim)) * x ----------------
// grid (8, 64)
__global__ __launch_bounds__(256) void k2_local(
    const float* __restrict__ x, const float* __restrict__ sim,
    const float* __restrict__ rowmax, const float* __restrict__ scale_arr,
    unsigned short* __restrict__ local_bf) {
  const int cc = blockIdx.x, inst = blockIdx.y;
  const int b = inst >> 4, n = inst & 15, bh = n >> 2, bw = n & 3;
  __shared__ unsigned short As[CMP_ * 136];   // [80][px 128 pad 136] bf16
  const int t = threadIdx.x, lane = t & 63, w = t >> 6;
  const int lo = lane & 15, hi = lane >> 4;
  const int chw = cc * 64 + w * 16;
  const int cm0 = t >> 3, pq = t & 7;

  f32x4 acc[5];
#pragma unroll
  for (int T = 0; T < 5; ++T) acc[T] = (f32x4){0.f, 0.f, 0.f, 0.f};

  for (int pc = 0; pc < 8; ++pc) {
    __syncthreads();
#pragma unroll
    for (int j = 0; j < 3; ++j) {
      int cm = cm0 + 32 * j;
      if (cm < CMP_) {
        if (cm < CM_) {
          float rm = rowmax[inst * CM_ + cm];
          float sc = scale_arr[inst * CM_ + cm];
          const float* srow = sim + ((size_t)(b * CM_ + cm) << 14);
#pragma unroll
          for (int i = 0; i < 4; ++i) {
            int pxl = i * 32 + pq * 4;
            int gpx = pc * 128 + pxl;
            int pix = ((bh * 32 + (gpx >> 5)) << 7) + bw * 32 + (gpx & 31);
            float4 vv = *(const float4*)(srow + pix);
            unsigned l32 = pack2(sc * __expf(vv.x - rm), sc * __expf(vv.y - rm));
            unsigned h32 = pack2(sc * __expf(vv.z - rm), sc * __expf(vv.w - rm));
            *(unsigned long long*)(&As[cm * 136 + pxl]) =
                (unsigned long long)l32 | ((unsigned long long)h32 << 32);
          }
        } else {
#pragma unroll
          for (int i = 0; i < 4; ++i)
            *(unsigned long long*)(&As[cm * 136 + i * 32 + pq * 4]) = 0ull;
        }
      }
    }
    __syncthreads();
#pragma unroll
    for (int ks = 0; ks < 4; ++ks) {
      int gpx0 = pc * 128 + ks * 32 + hi * 8;
      int pix0 = ((bh * 32 + (gpx0 >> 5)) << 7) + bw * 32 + (gpx0 & 31);
      const float* xr = x + (((size_t)(b * 512 + chw + lo)) << 14) + pix0;
      float4 v0 = *(const float4*)(xr);
      float4 v1 = *(const float4*)(xr + 4);
      bf16x8 bfr;
      ((unsigned*)&bfr)[0] = pack2(v0.x, v0.y);
      ((unsigned*)&bfr)[1] = pack2(v0.z, v0.w);
      ((unsigned*)&bfr)[2] = pack2(v1.x, v1.y);
      ((unsigned*)&bfr)[3] = pack2(v1.z, v1.w);
#pragma unroll
      for (int T = 0; T < 5; ++T) {
        bf16x8 afr = *(bf16x8*)(&As[(T * 16 + lo) * 136 + ks * 32 + hi * 8]);
        acc[T] = __builtin_amdgcn_mfma_f32_16x16x32_bf16(afr, bfr, acc[T], 0, 0, 0);
      }
    }
  }
#pragma unroll
  for (int T = 0; T < 5; ++T)
#pragma unroll
    for (int r = 0; r < 4; ++r) {
      int cm = T * 16 + hi * 4 + r;
      if (cm < CM_)
        local_bf[((size_t)inst * CMP_ + cm) * 512 + chw + lo] = f2bf(acc[T][r]);
    }
}

// ---------------- kbk: bk2[inst][cm] = local.wkbq + cbb (pads -1e30) ----------------
// grid (64)
__global__ __launch_bounds__(256) void kbk(
    const unsigned short* __restrict__ local_bf, const float* __restrict__ wkbq,
    const float* __restrict__ cbbp, float* __restrict__ bk2) {
  const int inst = blockIdx.x, t = threadIdx.x;
  __shared__ float wsm[512];
  for (int i = t; i < 512; i += 256) wsm[i] = wkbq[i];
  __syncthreads();
  const float cbb = cbbp[0];
  const int q = t & 3;
#pragma unroll
  for (int base = 0; base < 128; base += 64) {
    int idx = base + (t >> 2);
    if (idx < CM_) {
      const unsigned short* row = local_bf + ((size_t)inst * CMP_ + idx) * 512 + q * 128;
      float s = 0.f;
      for (int j = 0; j < 128; j += 2) {
        unsigned u = *(const unsigned*)(row + j);
        s += bf2f((unsigned short)(u & 0xFFFF)) * wsm[q * 128 + j]
           + bf2f((unsigned short)(u >> 16)) * wsm[q * 128 + j + 1];
      }
      s += __shfl_down(s, 2);
      s += __shfl_down(s, 1);
      if (q == 0) bk2[inst * CMP_ + idx] = s + cbb;
    } else if (idx < CMP_ && q == 0) {
      bk2[inst * CMP_ + idx] = -1e30f;
    }
  }
}

// ---------------- k3n (MFMA): Wqkt[inst][cm][c] = local@WqWkT^T + bqkadd ----------------
// grid (4, 64): blk.x = 128-c tile, inst. No LDS, direct global frags.
__global__ __launch_bounds__(256) void k3n_wqkt(
    const unsigned short* __restrict__ local_bf, const unsigned short* __restrict__ WqWkT,
    const float* __restrict__ bqkadd, unsigned short* __restrict__ Wqkt) {
  const int blkc = blockIdx.x, inst = blockIdx.y;
  const int t = threadIdx.x, lane = t & 63, w = t >> 6;
  const int lo = lane & 15, hi = lane >> 4;
  const int cbase = blkc * 128 + w * 32;
  f32x4 acc[5][2];
#pragma unroll
  for (int cT = 0; cT < 2; ++cT) {
    float bv_ = bqkadd[cbase + cT * 16 + lo];
#pragma unroll
    for (int T = 0; T < 5; ++T) acc[T][cT] = (f32x4){bv_, bv_, bv_, bv_};
  }
  const unsigned short* Abase = local_bf + (size_t)inst * 40960;
#pragma unroll 4
  for (int ks = 0; ks < 16; ++ks) {
    const int k = ks * 32 + hi * 8;
    bf16x8 af[5];
#pragma unroll
    for (int T = 0; T < 5; ++T)
      af[T] = *(const bf16x8*)(Abase + (size_t)(T * 16 + lo) * 512 + k);
#pragma unroll
    for (int cT = 0; cT < 2; ++cT) {
      bf16x8 bfr = *(const bf16x8*)(WqWkT + (size_t)(cbase + cT * 16 + lo) * 512 + k);
#pragma unroll
      for (int T = 0; T < 5; ++T)
        acc[T][cT] = __builtin_amdgcn_mfma_f32_16x16x32_bf16(af[T], bfr, acc[T][cT], 0, 0, 0);
    }
  }
#pragma unroll
  for (int T = 0; T < 5; ++T)
#pragma unroll
    for (int cT = 0; cT < 2; ++cT)
#pragma unroll
      for (int r = 0; r < 4; ++r) {
        int cm = T * 16 + hi * 4 + r;
        Wqkt[(size_t)inst * 40960 + (size_t)cm * 512 + cbase + cT * 16 + lo] =
            f2bf(acc[T][cT][r]);
      }
}

// ---------------- kV (MFMA): vWt[c2][cm] = WvWcT@g^T + bvWc ----------------
// grid (8, 2): blk.x = 64 c2-rows, blk.y = cm half
__global__ __launch_bounds__(256) void kV_vwt(
    const unsigned short* __restrict__ WvWcT, const float* __restrict__ g,
    const float* __restrict__ bv, const float* __restrict__ Wc,
    unsigned short* __restrict__ vWt) {
  const int blk = blockIdx.x, half = blockIdx.y;
  const int t = threadIdx.x, lane = t & 63, w = t >> 6;
  const int lo = lane & 15, hi = lane >> 4;
  __shared__ float bvp[4][64];
  __shared__ float bvs[64];
  {
    int c2l = t & 63, part = t >> 6;
    float s = 0.f;
    for (int m = part * 64; m < part * 64 + 64; ++m)
      s += bv[m] * Wc[(size_t)m * 512 + blk * 64 + c2l];
    bvp[part][c2l] = s;
  }
  __syncthreads();
  if (t < 64) bvs[t] = bvp[0][t] + bvp[1][t] + bvp[2][t] + bvp[3][t];
  __syncthreads();
  const int r2 = blk * 64 + w * 16;
  f32x4 acc[3];
#pragma unroll
  for (int j = 0; j < 3; ++j) acc[j] = (f32x4){0.f, 0.f, 0.f, 0.f};
#pragma unroll 4
  for (int ks = 0; ks < 16; ++ks) {
    const int k = ks * 32 + hi * 8;
    bf16x8 afr = *(const bf16x8*)(WvWcT + (size_t)(r2 + lo) * 512 + k);
#pragma unroll
    for (int j = 0; j < 3; ++j) {
      int cm = (half * 3 + j) * 16 + lo;
      cm = cm > 75 ? 75 : cm;
      const float* gr = g + (size_t)cm * 512 + k;
      float4 v0 = *(const float4*)gr, v1 = *(const float4*)(gr + 4);
      bf16x8 bfr;
      ((unsigned*)&bfr)[0] = pack2(v0.x, v0.y);
      ((unsigned*)&bfr)[1] = pack2(v0.z, v0.w);
      ((unsigned*)&bfr)[2] = pack2(v1.x, v1.y);
      ((unsigned*)&bfr)[3] = pack2(v1.z, v1.w);
      acc[j] = __builtin_amdgcn_mfma_f32_16x16x32_bf16(afr, bfr, acc[j], 0, 0, 0);
    }
  }
#pragma unroll
  for (int j = 0; j < 3; ++j)
#pragma unroll
    for (int rr = 0; rr < 4; ++rr) {
      int c2g = blk * 64 + w * 16 + hi * 4 + rr;
      vWt[(size_t)c2g * 96 + (half * 3 + j) * 16 + lo] =
          f2bf(acc[j][rr] + bvs[w * 16 + hi * 4 + rr]);
    }
}

// ---------------- K4 (MFMA): logits -> in-register softmax -> y (BN+ReLU) ----------------
// grid (8, 64)
__global__ __launch_bounds__(256) void k4_attn(
    const float* __restrict__ x, const unsigned short* __restrict__ Wqkt,
    const float* __restrict__ bk2, const unsigned short* __restrict__ vWt,
    const float* __restrict__ inv_arr, const float* __restrict__ add_arr,
    float* __restrict__ y) {
  const int pt = blockIdx.x, inst = blockIdx.y;
  const int b = inst >> 4, n = inst & 15, bh = n >> 2, bw = n & 3;
  __shared__ unsigned short Xs[4][32 * 72];
  __shared__ unsigned short Att[4][32 * 96];
  __shared__ float bn_s[1024];
  const int t = threadIdx.x, lane = t & 63, w = t >> 6;
  const int lo = lane & 15, hi = lane >> 4;
  const int pq = lane & 7, chp0 = lane >> 3;

  for (int i = t; i < 512; i += 256) { bn_s[i] = inv_arr[i]; bn_s[512 + i] = add_arr[i]; }

  const int imgrow = bh * 32 + pt * 4 + w;
  const size_t pixbase = (size_t)imgrow * 128 + bw * 32;
  const size_t xrowbase = (((size_t)b * 512) << 14) + pixbase;
  const unsigned short* Wi = Wqkt + (size_t)inst * 40960;

  f32x4 acc[2][5];
#pragma unroll
  for (int T = 0; T < 5; ++T) {
    f32x4 bv;
#pragma unroll
    for (int r = 0; r < 4; ++r) bv[r] = bk2[inst * CMP_ + T * 16 + hi * 4 + r];
    acc[0][T] = bv; acc[1][T] = bv;
  }

  for (int kc = 0; kc < 8; ++kc) {
#pragma unroll
    for (int i = 0; i < 4; ++i) {
      int chp = chp0 + i * 8;
      int ch = kc * 64 + chp * 2;
      const float* xa = x + xrowbase + ((size_t)ch << 14) + pq * 4;
      float4 va = *(const float4*)(xa);
      float4 vb = *(const float4*)(xa + 16384);
      unsigned short* dst = &Xs[w][(pq * 4) * 72 + chp * 2];
      *(unsigned*)(dst + 0 * 72) = pack2(va.x, vb.x);
      *(unsigned*)(dst + 1 * 72) = pack2(va.y, vb.y);
      *(unsigned*)(dst + 2 * 72) = pack2(va.z, vb.z);
      *(unsigned*)(dst + 3 * 72) = pack2(va.w, vb.w);
    }
#pragma unroll
    for (int ks = 0; ks < 2; ++ks) {
      int kb = kc * 64 + ks * 32 + hi * 8;
      bf16x8 b0 = *(bf16x8*)(&Xs[w][lo * 72 + ks * 32 + hi * 8]);
      bf16x8 b1 = *(bf16x8*)(&Xs[w][(16 + lo) * 72 + ks * 32 + hi * 8]);
#pragma unroll
      for (int T = 0; T < 5; ++T) {
        bf16x8 afr = *(const bf16x8*)(Wi + (size_t)(T * 16 + lo) * 512 + kb);
        acc[0][T] = __builtin_amdgcn_mfma_f32_16x16x32_bf16(afr, b0, acc[0][T], 0, 0, 0);
        acc[1][T] = __builtin_amdgcn_mfma_f32_16x16x32_bf16(afr, b1, acc[1][T], 0, 0, 0);
      }
    }
  }

#pragma unroll
  for (int p = 0; p < 2; ++p) {
    float m = -1e30f;
#pragma unroll
    for (int T = 0; T < 5; ++T)
#pragma unroll
      for (int r = 0; r < 4; ++r) m = fmaxf(m, acc[p][T][r]);
    m = fmaxf(m, __shfl_xor(m, 16));
    m = fmaxf(m, __shfl_xor(m, 32));
    float e[5][4];
    float s = 0.f;
#pragma unroll
    for (int T = 0; T < 5; ++T)
#pragma unroll
      for (int r = 0; r < 4; ++r) { float ev = __expf(acc[p][T][r] - m); e[T][r] = ev; s += ev; }
    s += __shfl_xor(s, 16);
    s += __shfl_xor(s, 32);
    float rinv = 1.f / s;
    int px = p * 16 + lo;
#pragma unroll
    for (int T = 0; T < 5; ++T) {
      unsigned l32 = pack2(e[T][0] * rinv, e[T][1] * rinv);
      unsigned h32 = pack2(e[T][2] * rinv, e[T][3] * rinv);
      *(unsigned long long*)(&Att[w][px * 96 + T * 16 + hi * 4]) =
          (unsigned long long)l32 | ((unsigned long long)h32 << 32);
    }
    *(unsigned long long*)(&Att[w][px * 96 + 80 + hi * 4]) = 0ull;
  }

  __syncthreads();

  bf16x8 bfr3[2][3];
#pragma unroll
  for (int p = 0; p < 2; ++p)
#pragma unroll
    for (int ks = 0; ks < 3; ++ks)
      bfr3[p][ks] = *(bf16x8*)(&Att[w][(p * 16 + lo) * 96 + ks * 32 + hi * 8]);

  for (int cT = 0; cT < 32; ++cT) {
    f32x4 a0 = (f32x4){0.f, 0.f, 0.f, 0.f}, a1 = a0;
    const unsigned short* vr = vWt + (size_t)(cT * 16 + lo) * 96;
#pragma unroll
    for (int ks = 0; ks < 3; ++ks) {
      bf16x8 afr = *(const bf16x8*)(vr + ks * 32 + hi * 8);
      a0 = __builtin_amdgcn_mfma_f32_16x16x32_bf16(afr, bfr3[0][ks], a0, 0, 0, 0);
      a1 = __builtin_amdgcn_mfma_f32_16x16x32_bf16(afr, bfr3[1][ks], a1, 0, 0, 0);
    }
    f32x4 inv4 = *(f32x4*)(&bn_s[cT * 16 + hi * 4]);
    f32x4 add4 = *(f32x4*)(&bn_s[512 + cT * 16 + hi * 4]);
#pragma unroll
    for (int r = 0; r < 4; ++r) {
      int ch = cT * 16 + hi * 4 + r;
      float v0 = fmaxf(a0[r] * inv4[r] + add4[r], 0.f);
      float v1 = fmaxf(a1[r] * inv4[r] + add4[r], 0.f);
      size_t yb = (((size_t)(b * 512 + ch)) << 14) + pixbase;
      y[yb + lo] = v0;
      y[yb + 16 + lo] = v1;
    }
  }
}

// ---------------- host launch ----------------
extern "C" void kernel_launch(void* const* d_in, const int* in_sizes, int n_in,
                              void* d_out, int out_size, void* d_ws, size_t ws_size,
                              hipStream_t stream) {
  (void)in_sizes; (void)n_in; (void)out_size; (void)ws_size;
  const float* x     = (const float*)d_in[0];
  const float* sim   = (const float*)d_in[1];
  const float* g     = (const float*)d_in[2];
  const float* Wq    = (const float*)d_in[3];
  const float* bq    = (const float*)d_in[4];
  const float* Wk    = (const float*)d_in[5];
  const float* bk    = (const float*)d_in[6];
  const float* Wv    = (const float*)d_in[7];
  const float* bv    = (const float*)d_in[8];
  const float* Wc    = (const float*)d_in[9];
  const float* gamma = (const float*)d_in[10];
  const float* beta  = (const float*)d_in[11];
  const float* mean  = (const float*)d_in[12];
  const float* var   = (const float*)d_in[13];
  float* out = (float*)d_out;
  float* ws  = (float*)d_ws;
  float* y   = out;                    // [4][512][128][128]
  float* pcs = out + 33554432;         // [4][76][4][4]
  unsigned short* localbf = (unsigned short*)(ws + OFF_LOCALBF);
  unsigned short* Wqkt    = (unsigned short*)(ws + OFF_WQKT);
  unsigned short* vWt     = (unsigned short*)(ws + OFF_VWT);
  unsigned short* WqWkT   = (unsigned short*)(ws + OFF_WQWKT);
  unsigned short* WvWcT   = (unsigned short*)(ws + OFF_WVWCT);

  hipLaunchKernelGGL(kW_pre, dim3(64, 2), dim3(256), 0, stream,
                     Wq, Wk, Wv, Wc, WqWkT, WvWcT);
  hipLaunchKernelGGL(kB_pre, dim3(2), dim3(256), 0, stream,
                     Wk, Wq, bq, bk, gamma, beta, mean, var,
                     ws + OFF_WKBQ, ws + OFF_BQKADD, ws + OFF_INV, ws + OFF_ADD,
                     ws + OFF_CBB);
  hipLaunchKernelGGL(k1_stats, dim3(CM_, 64), dim3(256), 0, stream,
                     sim, pcs, ws + OFF_ROWMAX, ws + OFF_SCALE);
  hipLaunchKernelGGL(k2_local, dim3(8, 64), dim3(256), 0, stream,
                     x, sim, ws + OFF_ROWMAX, ws + OFF_SCALE, localbf);
  hipLaunchKernelGGL(kbk, dim3(64), dim3(256), 0, stream,
                     localbf, ws + OFF_WKBQ, ws + OFF_CBB, ws + OFF_BK2);
  hipLaunchKernelGGL(k3n_wqkt, dim3(4, 64), dim3(256), 0, stream,
                     localbf, WqWkT, ws + OFF_BQKADD, Wqkt);
  hipLaunchKernelGGL(kV_vwt, dim3(8, 2), dim3(256), 0, stream,
                     WvWcT, g, bv, Wc, vWt);
  hipLaunchKernelGGL(k4_attn, dim3(8, 64), dim3(256), 0, stream,
                     x, Wqkt, ws + OFF_BK2, vWt,
                     ws + OFF_INV, ws + OFF_ADD, y);
}

// Round 4
// 424.775 us; speedup vs baseline: 2.0407x; 1.0143x over previous
//
#include <hip/hip_runtime.h>

// ---------------- problem constants ----------------
// b=4, C=512, h=w=128, BH=BW=4 -> 64 instances, P=1024 pixels each
// CM=76 (pad 80/96), mid=256
#define CM_    76
#define CMP_   80

typedef __attribute__((ext_vector_type(4))) float f32x4;
typedef __attribute__((ext_vector_type(8))) short bf16x8;

__device__ __forceinline__ unsigned short f2bf(float f) {
  union { float f; unsigned u; } v; v.f = f;
  unsigned r = v.u + 0x7FFFu + ((v.u >> 16) & 1u);
  return (unsigned short)(r >> 16);
}
__device__ __forceinline__ unsigned pack2(float a, float b) {
  return (unsigned)f2bf(a) | ((unsigned)f2bf(b) << 16);
}

// ---------------- workspace layout (float offsets; all 16B-aligned) ----------------
#define OFF_BK2     0            // [64][80] f32 (init cbb / -1e30 pads, k2 atomics add)
#define OFF_INV     5120         // [512] f32
#define OFF_ADD     5632         // [512] f32
#define OFF_WKBQ    6144         // [512] f32  (Wk@bq)
#define OFF_BQKADD  6656         // [512] f32  (Wq@bk)
#define OFF_CBB     7168         // [1] f32 (pad to 7172)
#define OFF_EXPSIM  7172         // bf16 [64][80][1024]  (2,621,440 f)
#define OFF_LOCALBF 2628612      // bf16 [64][80][512]   (1,310,720 f)
#define OFF_WQKT    3939332      // bf16 [64][80][512]
#define OFF_VWT     5250052      // bf16 [512][96]
#define OFF_WQWKT   5274628      // bf16 [512][512] (Wq@Wk^T)
#define OFF_WVWCT   5405700      // bf16 [512][512] (Wc^T@Wv^T)
// total 5,536,772 floats = 22.1 MB

// ---------------- kW (one-off): WqWkT / WvWcT + (blk.x==64) scalar pre ----------------
// grid (65, 2)
__global__ __launch_bounds__(256) void kW_pre(
    const float* __restrict__ Wq, const float* __restrict__ Wk,
    const float* __restrict__ Wv, const float* __restrict__ Wc,
    const float* __restrict__ bq, const float* __restrict__ bk,
    const float* __restrict__ gamma, const float* __restrict__ beta,
    const float* __restrict__ mean, const float* __restrict__ var,
    unsigned short* __restrict__ WqWkT, unsigned short* __restrict__ WvWcT,
    float* __restrict__ wkbq, float* __restrict__ bqkadd,
    float* __restrict__ invp, float* __restrict__ addp, float* __restrict__ cbbp) {
  const int sel = blockIdx.y;
  if (blockIdx.x == 64) {       // scalar pre-kernel half (c = sel*256 + t)
    const int c = sel * 256 + threadIdx.x;
    const float* wkr = Wk + (size_t)c * 256;
    const float* wqr = Wq + (size_t)c * 256;
    float s1 = 0.f, s2 = 0.f;
    for (int m = 0; m < 256; ++m) { s1 += wkr[m] * bq[m]; s2 += wqr[m] * bk[m]; }
    wkbq[c] = s1; bqkadd[c] = s2;
    float iv = gamma[c] * rsqrtf(var[c] + 1e-5f);
    invp[c] = iv; addp[c] = beta[c] - mean[c] * iv;
    if (c == 0) {
      float s = 0.f;
      for (int m = 0; m < 256; ++m) s += bq[m] * bk[m];
      cbbp[0] = s;
    }
    return;
  }
  const int r0 = (blockIdx.x >> 3) * 64, c0 = (blockIdx.x & 7) * 64;
  __shared__ __align__(16) unsigned short Asm[64 * 40];
  __shared__ __align__(16) unsigned short Bsm[64 * 40];
  const int t = threadIdx.x, lane = t & 63, w = t >> 6;
  const int lo = lane & 15, hi = lane >> 4;
  f32x4 acc[4];
#pragma unroll
  for (int cT = 0; cT < 4; ++cT) acc[cT] = (f32x4){0.f, 0.f, 0.f, 0.f};
  const float* Bsrc = sel ? Wv : Wk;
  for (int kc = 0; kc < 8; ++kc) {
    const int k0 = kc * 32;
    __syncthreads();
    {
      int nn = t >> 2, mq = (t & 3) * 8;
      const float* src = Bsrc + (size_t)(c0 + nn) * 256 + k0 + mq;
      float4 v0 = *(const float4*)src, v1 = *(const float4*)(src + 4);
      unsigned* d = (unsigned*)&Bsm[nn * 40 + mq];
      d[0] = pack2(v0.x, v0.y); d[1] = pack2(v0.z, v0.w);
      d[2] = pack2(v1.x, v1.y); d[3] = pack2(v1.z, v1.w);
    }
    if (sel == 0) {
      int r = t >> 2, mq = (t & 3) * 8;
      const float* src = Wq + (size_t)(r0 + r) * 256 + k0 + mq;
      float4 v0 = *(const float4*)src, v1 = *(const float4*)(src + 4);
      unsigned* d = (unsigned*)&Asm[r * 40 + mq];
      d[0] = pack2(v0.x, v0.y); d[1] = pack2(v0.z, v0.w);
      d[2] = pack2(v1.x, v1.y); d[3] = pack2(v1.z, v1.w);
    } else {
      int m = t >> 3, c2q = (t & 7) * 8;
      const float* src = Wc + (size_t)(k0 + m) * 512 + r0 + c2q;
      float4 v0 = *(const float4*)src, v1 = *(const float4*)(src + 4);
      Asm[(c2q + 0) * 40 + m] = f2bf(v0.x); Asm[(c2q + 1) * 40 + m] = f2bf(v0.y);
      Asm[(c2q + 2) * 40 + m] = f2bf(v0.z); Asm[(c2q + 3) * 40 + m] = f2bf(v0.w);
      Asm[(c2q + 4) * 40 + m] = f2bf(v1.x); Asm[(c2q + 5) * 40 + m] = f2bf(v1.y);
      Asm[(c2q + 6) * 40 + m] = f2bf(v1.z); Asm[(c2q + 7) * 40 + m] = f2bf(v1.w);
    }
    __syncthreads();
    bf16x8 afr = *(bf16x8*)(&Asm[(w * 16 + lo) * 40 + hi * 8]);
#pragma unroll
    for (int cT = 0; cT < 4; ++cT) {
      bf16x8 bfr = *(bf16x8*)(&Bsm[(cT * 16 + lo) * 40 + hi * 8]);
      acc[cT] = __builtin_amdgcn_mfma_f32_16x16x32_bf16(afr, bfr, acc[cT], 0, 0, 0);
    }
  }
  unsigned short* dst = sel ? WvWcT : WqWkT;
#pragma unroll
  for (int cT = 0; cT < 4; ++cT)
#pragma unroll
    for (int rr = 0; rr < 4; ++rr)
      dst[(size_t)(r0 + w * 16 + hi * 4 + rr) * 512 + c0 + cT * 16 + lo] = f2bf(acc[cT][rr]);
}

// ---------------- K1: stats + materialize expsim bf16 (scaled), init bk2 ----------------
// grid (80, 64), block 256
__global__ __launch_bounds__(256) void k1_stats(
    const float* __restrict__ sim, float* __restrict__ pcs,
    const float* __restrict__ cbbp,
    unsigned short* __restrict__ expsim, float* __restrict__ bk2) {
  const int cm = blockIdx.x, inst = blockIdx.y;
  const int t = threadIdx.x;
  unsigned short* erow = expsim + (size_t)inst * 81920 + (size_t)cm * 1024;
  if (cm >= CM_) {                          // pad rows: zero, bk2 = -inf
    ((unsigned long long*)erow)[t] = 0ull;
    if (t == 0) bk2[inst * CMP_ + cm] = -1e30f;
    return;
  }
  const int b = inst >> 4, n = inst & 15, bh = n >> 2, bw = n & 3;
  const float* base = sim + ((size_t)(b * CM_ + cm) << 14);
  float v[4];
  float lsum = 0.f, lmax = -1e30f;
#pragma unroll
  for (int i = 0; i < 4; ++i) {
    int p = t + (i << 8);
    int pix = ((bh * 32 + (p >> 5)) << 7) + bw * 32 + (p & 31);
    float xv = base[pix];
    v[i] = xv; lsum += xv; lmax = fmaxf(lmax, xv);
  }
#pragma unroll
  for (int off = 32; off; off >>= 1) {
    lsum += __shfl_down(lsum, off);
    lmax = fmaxf(lmax, __shfl_down(lmax, off));
  }
  __shared__ float ssum[4], smax[4], bc[2];
  const int wid = t >> 6;
  if ((t & 63) == 0) { ssum[wid] = lsum; smax[wid] = lmax; }
  __syncthreads();
  if (t == 0) {
    bc[0] = ssum[0] + ssum[1] + ssum[2] + ssum[3];
    bc[1] = fmaxf(fmaxf(smax[0], smax[1]), fmaxf(smax[2], smax[3]));
  }
  __syncthreads();
  const float M = bc[1];
  float le = 0.f;
#pragma unroll
  for (int i = 0; i < 4; ++i) le += __expf(v[i] - M);
#pragma unroll
  for (int off = 32; off; off >>= 1) le += __shfl_down(le, off);
  if ((t & 63) == 0) ssum[wid] = le;
  __syncthreads();
  if (t == 0) {
    float E = ssum[0] + ssum[1] + ssum[2] + ssum[3];
    float conf = bc[0] * (1.f / 1024.f);
    pcs[((b * CM_ + cm) << 4) + n] = conf;
    bk2[inst * CMP_ + cm] = cbbp[0];        // base for k2's atomic accumulation
    bc[0] = conf / E;                        // broadcast scale
  }
  __syncthreads();
  const float sc = bc[0];
#pragma unroll
  for (int i = 0; i < 4; ++i) {
    int p = t + (i << 8);
    erow[p] = f2bf(sc * __expf(v[i] - M));
  }
}

// ---------------- K2 (MFMA, no LDS): local bf16 = expsim @ x^T ; bk2 += local.wkbq ----------------
// grid (8, 64): cc = 64-ch block; each wave owns 16 ch.
__global__ __launch_bounds__(256) void k2_local(
    const float* __restrict__ x, const unsigned short* __restrict__ expsim,
    const float* __restrict__ wkbq,
    unsigned short* __restrict__ local_bf, float* __restrict__ bk2) {
  const int cc = blockIdx.x, inst = blockIdx.y;
  const int b = inst >> 4, n = inst & 15, bh = n >> 2, bw = n & 3;
  const int t = threadIdx.x, lane = t & 63, w = t >> 6;
  const int lo = lane & 15, hi = lane >> 4;
  const int chw = cc * 64 + w * 16;
  const unsigned short* Abase = expsim + (size_t)inst * 81920;
  const float* xch = x + (((size_t)(b * 512 + chw + lo)) << 14) + bw * 32 + hi * 8;
  const int rowb = bh * 32;
  f32x4 acc[5];
#pragma unroll
  for (int T = 0; T < 5; ++T) acc[T] = (f32x4){0.f, 0.f, 0.f, 0.f};
#pragma unroll 4
  for (int ks = 0; ks < 32; ++ks) {
    const int k = ks * 32 + hi * 8;           // global patch-linear px
    const float* xr = xch + ((size_t)(rowb + ks) << 7);
    float4 v0 = *(const float4*)(xr);
    float4 v1 = *(const float4*)(xr + 4);
    bf16x8 bfr;
    ((unsigned*)&bfr)[0] = pack2(v0.x, v0.y);
    ((unsigned*)&bfr)[1] = pack2(v0.z, v0.w);
    ((unsigned*)&bfr)[2] = pack2(v1.x, v1.y);
    ((unsigned*)&bfr)[3] = pack2(v1.z, v1.w);
#pragma unroll
    for (int T = 0; T < 5; ++T) {
      bf16x8 afr = *(const bf16x8*)(Abase + (size_t)(T * 16 + lo) * 1024 + k);
      acc[T] = __builtin_amdgcn_mfma_f32_16x16x32_bf16(afr, bfr, acc[T], 0, 0, 0);
    }
  }
  // epilogue: write local (pads exact 0), fold bk2 dot via lane-reduce + atomic
  const float wk = wkbq[chw + lo];
#pragma unroll
  for (int T = 0; T < 5; ++T)
#pragma unroll
    for (int r = 0; r < 4; ++r) {
      int cm = T * 16 + hi * 4 + r;
      float av = acc[T][r];
      local_bf[((size_t)inst * CMP_ + cm) * 512 + chw + lo] = f2bf(av);
      float p = av * wk;
      p += __shfl_xor(p, 1); p += __shfl_xor(p, 2);
      p += __shfl_xor(p, 4); p += __shfl_xor(p, 8);
      if (lo == 0 && cm < CM_) atomicAdd(&bk2[inst * CMP_ + cm], p);
    }
}

// ---------------- k3n (MFMA): Wqkt[inst][cm][c] = local@WqWkT^T + bqkadd ----------------
// grid (4, 64)
__global__ __launch_bounds__(256) void k3n_wqkt(
    const unsigned short* __restrict__ local_bf, const unsigned short* __restrict__ WqWkT,
    const float* __restrict__ bqkadd, unsigned short* __restrict__ Wqkt) {
  const int blkc = blockIdx.x, inst = blockIdx.y;
  const int t = threadIdx.x, lane = t & 63, w = t >> 6;
  const int lo = lane & 15, hi = lane >> 4;
  const int cbase = blkc * 128 + w * 32;
  f32x4 acc[5][2];
#pragma unroll
  for (int cT = 0; cT < 2; ++cT) {
    float bv_ = bqkadd[cbase + cT * 16 + lo];
#pragma unroll
    for (int T = 0; T < 5; ++T) acc[T][cT] = (f32x4){bv_, bv_, bv_, bv_};
  }
  const unsigned short* Abase = local_bf + (size_t)inst * 40960;
#pragma unroll 4
  for (int ks = 0; ks < 16; ++ks) {
    const int k = ks * 32 + hi * 8;
    bf16x8 af[5];
#pragma unroll
    for (int T = 0; T < 5; ++T)
      af[T] = *(const bf16x8*)(Abase + (size_t)(T * 16 + lo) * 512 + k);
#pragma unroll
    for (int cT = 0; cT < 2; ++cT) {
      bf16x8 bfr = *(const bf16x8*)(WqWkT + (size_t)(cbase + cT * 16 + lo) * 512 + k);
#pragma unroll
      for (int T = 0; T < 5; ++T)
        acc[T][cT] = __builtin_amdgcn_mfma_f32_16x16x32_bf16(af[T], bfr, acc[T][cT], 0, 0, 0);
    }
  }
#pragma unroll
  for (int T = 0; T < 5; ++T)
#pragma unroll
    for (int cT = 0; cT < 2; ++cT)
#pragma unroll
      for (int r = 0; r < 4; ++r) {
        int cm = T * 16 + hi * 4 + r;
        Wqkt[(size_t)inst * 40960 + (size_t)cm * 512 + cbase + cT * 16 + lo] =
            f2bf(acc[T][cT][r]);
      }
}

// ---------------- kV (MFMA): vWt[c2][cm] = WvWcT@g^T + bvWc ----------------
// grid (8, 2)
__global__ __launch_bounds__(256) void kV_vwt(
    const unsigned short* __restrict__ WvWcT, const float* __restrict__ g,
    const float* __restrict__ bv, const float* __restrict__ Wc,
    unsigned short* __restrict__ vWt) {
  const int blk = blockIdx.x, half = blockIdx.y;
  const int t = threadIdx.x, lane = t & 63, w = t >> 6;
  const int lo = lane & 15, hi = lane >> 4;
  __shared__ float bvp[4][64];
  __shared__ float bvs[64];
  {
    int c2l = t & 63, part = t >> 6;
    float s = 0.f;
    for (int m = part * 64; m < part * 64 + 64; ++m)
      s += bv[m] * Wc[(size_t)m * 512 + blk * 64 + c2l];
    bvp[part][c2l] = s;
  }
  __syncthreads();
  if (t < 64) bvs[t] = bvp[0][t] + bvp[1][t] + bvp[2][t] + bvp[3][t];
  __syncthreads();
  const int r2 = blk * 64 + w * 16;
  f32x4 acc[3];
#pragma unroll
  for (int j = 0; j < 3; ++j) acc[j] = (f32x4){0.f, 0.f, 0.f, 0.f};
#pragma unroll 4
  for (int ks = 0; ks < 16; ++ks) {
    const int k = ks * 32 + hi * 8;
    bf16x8 afr = *(const bf16x8*)(WvWcT + (size_t)(r2 + lo) * 512 + k);
#pragma unroll
    for (int j = 0; j < 3; ++j) {
      int cm = (half * 3 + j) * 16 + lo;
      cm = cm > 75 ? 75 : cm;
      const float* gr = g + (size_t)cm * 512 + k;
      float4 v0 = *(const float4*)gr, v1 = *(const float4*)(gr + 4);
      bf16x8 bfr;
      ((unsigned*)&bfr)[0] = pack2(v0.x, v0.y);
      ((unsigned*)&bfr)[1] = pack2(v0.z, v0.w);
      ((unsigned*)&bfr)[2] = pack2(v1.x, v1.y);
      ((unsigned*)&bfr)[3] = pack2(v1.z, v1.w);
      acc[j] = __builtin_amdgcn_mfma_f32_16x16x32_bf16(afr, bfr, acc[j], 0, 0, 0);
    }
  }
#pragma unroll
  for (int j = 0; j < 3; ++j)
#pragma unroll
    for (int rr = 0; rr < 4; ++rr) {
      int c2g = blk * 64 + w * 16 + hi * 4 + rr;
      vWt[(size_t)c2g * 96 + (half * 3 + j) * 16 + lo] =
          f2bf(acc[j][rr] + bvs[w * 16 + hi * 4 + rr]);
    }
}

// ---------------- K4 (MFMA): logits -> in-register softmax -> y (BN+ReLU) ----------------
// grid (8, 64)
__global__ __launch_bounds__(256) void k4_attn(
    const float* __restrict__ x, const unsigned short* __restrict__ Wqkt,
    const float* __restrict__ bk2, const unsigned short* __restrict__ vWt,
    const float* __restrict__ inv_arr, const float* __restrict__ add_arr,
    float* __restrict__ y) {
  const int pt = blockIdx.x, inst = blockIdx.y;
  const int b = inst >> 4, n = inst & 15, bh = n >> 2, bw = n & 3;
  __shared__ unsigned short Xs[4][32 * 72];
  __shared__ unsigned short Att[4][32 * 96];
  __shared__ float bn_s[1024];
  const int t = threadIdx.x, lane = t & 63, w = t >> 6;
  const int lo = lane & 15, hi = lane >> 4;
  const int pq = lane & 7, chp0 = lane >> 3;

  for (int i = t; i < 512; i += 256) { bn_s[i] = inv_arr[i]; bn_s[512 + i] = add_arr[i]; }

  const int imgrow = bh * 32 + pt * 4 + w;
  const size_t pixbase = (size_t)imgrow * 128 + bw * 32;
  const size_t xrowbase = (((size_t)b * 512) << 14) + pixbase;
  const unsigned short* Wi = Wqkt + (size_t)inst * 40960;

  f32x4 acc[2][5];
#pragma unroll
  for (int T = 0; T < 5; ++T) {
    f32x4 bv;
#pragma unroll
    for (int r = 0; r < 4; ++r) bv[r] = bk2[inst * CMP_ + T * 16 + hi * 4 + r];
    acc[0][T] = bv; acc[1][T] = bv;
  }

  for (int kc = 0; kc < 8; ++kc) {
#pragma unroll
    for (int i = 0; i < 4; ++i) {
      int chp = chp0 + i * 8;
      int ch = kc * 64 + chp * 2;
      const float* xa = x + xrowbase + ((size_t)ch << 14) + pq * 4;
      float4 va = *(const float4*)(xa);
      float4 vb = *(const float4*)(xa + 16384);
      unsigned short* dst = &Xs[w][(pq * 4) * 72 + chp * 2];
      *(unsigned*)(dst + 0 * 72) = pack2(va.x, vb.x);
      *(unsigned*)(dst + 1 * 72) = pack2(va.y, vb.y);
      *(unsigned*)(dst + 2 * 72) = pack2(va.z, vb.z);
      *(unsigned*)(dst + 3 * 72) = pack2(va.w, vb.w);
    }
#pragma unroll
    for (int ks = 0; ks < 2; ++ks) {
      int kb = kc * 64 + ks * 32 + hi * 8;
      bf16x8 b0 = *(bf16x8*)(&Xs[w][lo * 72 + ks * 32 + hi * 8]);
      bf16x8 b1 = *(bf16x8*)(&Xs[w][(16 + lo) * 72 + ks * 32 + hi * 8]);
#pragma unroll
      for (int T = 0; T < 5; ++T) {
        bf16x8 afr = *(const bf16x8*)(Wi + (size_t)(T * 16 + lo) * 512 + kb);
        acc[0][T] = __builtin_amdgcn_mfma_f32_16x16x32_bf16(afr, b0, acc[0][T], 0, 0, 0);
        acc[1][T] = __builtin_amdgcn_mfma_f32_16x16x32_bf16(afr, b1, acc[1][T], 0, 0, 0);
      }
    }
  }

#pragma unroll
  for (int p = 0; p < 2; ++p) {
    float m = -1e30f;
#pragma unroll
    for (int T = 0; T < 5; ++T)
#pragma unroll
      for (int r = 0; r < 4; ++r) m = fmaxf(m, acc[p][T][r]);
    m = fmaxf(m, __shfl_xor(m, 16));
    m = fmaxf(m, __shfl_xor(m, 32));
    float e[5][4];
    float s = 0.f;
#pragma unroll
    for (int T = 0; T < 5; ++T)
#pragma unroll
      for (int r = 0; r < 4; ++r) { float ev = __expf(acc[p][T][r] - m); e[T][r] = ev; s += ev; }
    s += __shfl_xor(s, 16);
    s += __shfl_xor(s, 32);
    float rinv = 1.f / s;
    int px = p * 16 + lo;
#pragma unroll
    for (int T = 0; T < 5; ++T) {
      unsigned l32 = pack2(e[T][0] * rinv, e[T][1] * rinv);
      unsigned h32 = pack2(e[T][2] * rinv, e[T][3] * rinv);
      *(unsigned long long*)(&Att[w][px * 96 + T * 16 + hi * 4]) =
          (unsigned long long)l32 | ((unsigned long long)h32 << 32);
    }
    *(unsigned long long*)(&Att[w][px * 96 + 80 + hi * 4]) = 0ull;
  }

  __syncthreads();

  bf16x8 bfr3[2][3];
#pragma unroll
  for (int p = 0; p < 2; ++p)
#pragma unroll
    for (int ks = 0; ks < 3; ++ks)
      bfr3[p][ks] = *(bf16x8*)(&Att[w][(p * 16 + lo) * 96 + ks * 32 + hi * 8]);

  for (int cT = 0; cT < 32; ++cT) {
    f32x4 a0 = (f32x4){0.f, 0.f, 0.f, 0.f}, a1 = a0;
    const unsigned short* vr = vWt + (size_t)(cT * 16 + lo) * 96;
#pragma unroll
    for (int ks = 0; ks < 3; ++ks) {
      bf16x8 afr = *(const bf16x8*)(vr + ks * 32 + hi * 8);
      a0 = __builtin_amdgcn_mfma_f32_16x16x32_bf16(afr, bfr3[0][ks], a0, 0, 0, 0);
      a1 = __builtin_amdgcn_mfma_f32_16x16x32_bf16(afr, bfr3[1][ks], a1, 0, 0, 0);
    }
    f32x4 inv4 = *(f32x4*)(&bn_s[cT * 16 + hi * 4]);
    f32x4 add4 = *(f32x4*)(&bn_s[512 + cT * 16 + hi * 4]);
#pragma unroll
    for (int r = 0; r < 4; ++r) {
      int ch = cT * 16 + hi * 4 + r;
      float v0 = fmaxf(a0[r] * inv4[r] + add4[r], 0.f);
      float v1 = fmaxf(a1[r] * inv4[r] + add4[r], 0.f);
      size_t yb = (((size_t)(b * 512 + ch)) << 14) + pixbase;
      y[yb + lo] = v0;
      y[yb + 16 + lo] = v1;
    }
  }
}

// ---------------- host launch ----------------
extern "C" void kernel_launch(void* const* d_in, const int* in_sizes, int n_in,
                              void* d_out, int out_size, void* d_ws, size_t ws_size,
                              hipStream_t stream) {
  (void)in_sizes; (void)n_in; (void)out_size; (void)ws_size;
  const float* x     = (const float*)d_in[0];
  const float* sim   = (const float*)d_in[1];
  const float* g     = (const float*)d_in[2];
  const float* Wq    = (const float*)d_in[3];
  const float* bq    = (const float*)d_in[4];
  const float* Wk    = (const float*)d_in[5];
  const float* bk    = (const float*)d_in[6];
  const float* Wv    = (const float*)d_in[7];
  const float* bv    = (const float*)d_in[8];
  const float* Wc    = (const float*)d_in[9];
  const float* gamma = (const float*)d_in[10];
  const float* beta  = (const float*)d_in[11];
  const float* mean  = (const float*)d_in[12];
  const float* var   = (const float*)d_in[13];
  float* out = (float*)d_out;
  float* ws  = (float*)d_ws;
  float* y   = out;                    // [4][512][128][128]
  float* pcs = out + 33554432;         // [4][76][4][4]
  unsigned short* expsim  = (unsigned short*)(ws + OFF_EXPSIM);
  unsigned short* localbf = (unsigned short*)(ws + OFF_LOCALBF);
  unsigned short* Wqkt    = (unsigned short*)(ws + OFF_WQKT);
  unsigned short* vWt     = (unsigned short*)(ws + OFF_VWT);
  unsigned short* WqWkT   = (unsigned short*)(ws + OFF_WQWKT);
  unsigned short* WvWcT   = (unsigned short*)(ws + OFF_WVWCT);

  hipLaunchKernelGGL(kW_pre, dim3(65, 2), dim3(256), 0, stream,
                     Wq, Wk, Wv, Wc, bq, bk, gamma, beta, mean, var,
                     WqWkT, WvWcT, ws + OFF_WKBQ, ws + OFF_BQKADD,
                     ws + OFF_INV, ws + OFF_ADD, ws + OFF_CBB);
  hipLaunchKernelGGL(k1_stats, dim3(CMP_, 64), dim3(256), 0, stream,
                     sim, pcs, ws + OFF_CBB, expsim, ws + OFF_BK2);
  hipLaunchKernelGGL(k2_local, dim3(8, 64), dim3(256), 0, stream,
                     x, expsim, ws + OFF_WKBQ, localbf, ws + OFF_BK2);
  hipLaunchKernelGGL(k3n_wqkt, dim3(4, 64), dim3(256), 0, stream,
                     localbf, WqWkT, ws + OFF_BQKADD, Wqkt);
  hipLaunchKernelGGL(kV_vwt, dim3(8, 2), dim3(256), 0, stream,
                     WvWcT, g, bv, Wc, vWt);
  hipLaunchKernelGGL(k4_attn, dim3(8, 64), dim3(256), 0, stream,
                     x, Wqkt, ws + OFF_BK2, vWt,
                     ws + OFF_INV, ws + OFF_ADD, y);
}